// Round 12
// baseline (657.645 us; speedup 1.0000x reference)
//
#include <hip/hip_runtime.h>
#include <math.h>

#define B_  16
#define C_  192
#define N_  3136
#define BN_ 50176
#define K_  9
#define NC_ 100
#define PD_ 1024
#define NSEV 7
#define SEVCOLS 448

#define OUT_EATT 1600
#define OUT_PP   453184

typedef short bf16x8 __attribute__((ext_vector_type(8)));
typedef float f32x16 __attribute__((ext_vector_type(16)));

__device__ __forceinline__ unsigned int umaxu(unsigned int a, unsigned int b) { return a > b ? a : b; }
__device__ __forceinline__ unsigned int med3u(unsigned int a, unsigned int b, unsigned int c) {
    unsigned int d;
    asm("v_med3_u32 %0, %1, %2, %3" : "=v"(d) : "v"(a), "v"(b), "v"(c));
    return d;
}
// insert key into sorted-desc lk[12]: L'[0]=max(L0,x), L'[k]=med3(L[k-1],L[k],x)
__device__ __forceinline__ void ins12m(unsigned int (&lk)[12], unsigned int key) {
    unsigned int nk[12];
    nk[0] = umaxu(lk[0], key);
    #pragma unroll
    for (int k = 1; k < 12; ++k) nk[k] = med3u(lk[k - 1], lk[k], key);
    #pragma unroll
    for (int k = 0; k < 12; ++k) lk[k] = nk[k];
}

// lexicographic (val desc, idx asc) insertion (rescore)
template<int NL>
__device__ inline void ins_lex(float (&lv)[NL], int (&li)[NL], float v, int vi) {
    if (v > lv[NL-1] || (v == lv[NL-1] && vi < li[NL-1])) {
        #pragma unroll
        for (int k = 0; k < NL; ++k) {
            bool p = (v > lv[k]) || (v == lv[k] && vi < li[k]);
            float fv = p ? lv[k] : v; int fi = p ? li[k] : vi;
            lv[k] = p ? v : lv[k];    li[k] = p ? vi : li[k];
            v = fv; vi = fi;
        }
    }
}

__device__ inline unsigned int bf16_rne(unsigned int u) {
    return (u + 0x7fffu + ((u >> 16) & 1u)) & 0xffff0000u;
}

// ---------------- normalize: [B,C,N] -> XN f32, XS bf16 hi|lo split, NORMS ----
__global__ __launch_bounds__(256) void k_normalize(const float* __restrict__ in,
        float* __restrict__ xn, unsigned short* __restrict__ xsn,
        float* __restrict__ norms) {
    __shared__ float tile[C_][65];
    __shared__ float part[4][64];
    __shared__ float rnorm_s[64];
    int b = blockIdx.x & 15;
    int n0 = (blockIdx.x >> 4) * 64;
    int t = threadIdx.x;
    for (int f = t; f < C_ * 64; f += 256) {
        int c = f >> 6, n = f & 63;
        tile[c][n] = in[((size_t)b * C_ + c) * N_ + n0 + n];
    }
    __syncthreads();
    {
        int n = t & 63, qq = t >> 6;
        float s = 0.f;
        #pragma unroll
        for (int i = 0; i < 48; ++i) { float v = tile[qq * 48 + i][n]; s += v * v; }
        part[qq][n] = s;
    }
    __syncthreads();
    if (t < 64) {
        float tot = part[0][t] + part[1][t] + part[2][t] + part[3][t];
        float nrm = fmaxf(sqrtf(tot), 1e-12f);
        norms[(size_t)b * N_ + n0 + t] = nrm;
        rnorm_s[t] = 1.0f / nrm;
    }
    __syncthreads();
    for (int f = t; f < 64 * 96; f += 256) {
        int n = f / 96, cp = f - n * 96;
        int c = cp * 2;
        float r = rnorm_s[n];
        float v0 = tile[c][n] * r;
        float v1 = tile[c + 1][n] * r;
        size_t row = (size_t)b * N_ + n0 + n;
        *(float2*)(xn + row * C_ + c) = make_float2(v0, v1);
        unsigned int h0 = bf16_rne(__float_as_uint(v0));
        unsigned int h1 = bf16_rne(__float_as_uint(v1));
        unsigned int l0 = bf16_rne(__float_as_uint(v0 - __uint_as_float(h0)));
        unsigned int l1 = bf16_rne(__float_as_uint(v1 - __uint_as_float(h1)));
        unsigned int* xr = (unsigned int*)(xsn + row * 384);
        xr[cp]      = (h0 >> 16) | (h1 & 0xffff0000u);
        xr[96 + cp] = (l0 >> 16) | (l1 & 0xffff0000u);
    }
}

// ---------------- split conv_w / gnn_w to bf16 hi|lo; transpose w2 ------------
__global__ __launch_bounds__(256) void k_wsplit(const float* __restrict__ cw,
        const float* __restrict__ gw, const float* __restrict__ w2,
        unsigned short* __restrict__ wsc, unsigned short* __restrict__ wsg,
        float* __restrict__ w2t) {
    int id = blockIdx.x * 256 + threadIdx.x;   // 640*256 = 163840
    if (id < 128 * 192) {
        int k = id / 192, c = id - k * 192;
        float v = (k < 100) ? cw[k * 192 + c] : 0.f;
        unsigned int h = bf16_rne(__float_as_uint(v));
        wsc[(size_t)k * 384 + c] = (unsigned short)(h >> 16);
        wsc[(size_t)k * 384 + 192 + c] =
            (unsigned short)(bf16_rne(__float_as_uint(v - __uint_as_float(h))) >> 16);
    } else if (id < 61440) {
        int e = id - 128 * 192;
        int cc = e / 192, j = e - cc * 192;
        float v = gw[cc * 192 + j];
        unsigned int h = bf16_rne(__float_as_uint(v));
        wsg[(size_t)j * 384 + cc] = (unsigned short)(h >> 16);
        wsg[(size_t)j * 384 + 192 + cc] =
            (unsigned short)(bf16_rne(__float_as_uint(v - __uint_as_float(h))) >> 16);
    } else {
        int e2 = id - 61440;                   // 0..102399
        int jj = e2 >> 10, k = e2 & 1023;
        w2t[(size_t)jj * PD_ + k] = w2[(size_t)k * NC_ + jj];
    }
}

// stage one 32-col chunk via global_load_lds; NLW = glds per wave
#define STAGE32(DST, SRCBASE, NLW) { \
    const char* s_ = (SRCBASE); \
    _Pragma("unroll") \
    for (int q_ = 0; q_ < NLW; ++q_) \
        __builtin_amdgcn_global_load_lds( \
            (const __attribute__((address_space(1))) unsigned int*)(s_ + q_ * 32), \
            (__attribute__((address_space(3))) unsigned int*)((DST) + (w * NLW + q_) * 1024), 16, 0, 0); }

// stage one K-HALF of a 32-col chunk (12KB); NLW glds per wave (NLW*waves=12)
#define STAGEHALF(DST, BASE, COLB, KH, NLW) { \
    _Pragma("unroll") \
    for (int q_ = 0; q_ < NLW; ++q_) { \
        const char* s_ = (BASE) + (size_t)((COLB) + l31) * 768 + (KH) * 384 + (w * (NLW) + q_) * 32 + lh * 16; \
        __builtin_amdgcn_global_load_lds( \
            (const __attribute__((address_space(1))) unsigned int*)s_, \
            (__attribute__((address_space(3))) unsigned int*)((DST) + (w * (NLW) + q_) * 1024), 16, 0, 0); } }

// 16-candidate packed-key scan into lk[12] (med3); off-diagonal chunk (no self test)
#define SCAN16 { \
    int c0 = cbase + c * 32 + 4 * lh; \
    int kc = 4095 - c0; \
    _Pragma("unroll") \
    for (int g = 0; g < 4; ++g) { \
        _Pragma("unroll") \
        for (int q = 0; q < 4; ++q) { \
            unsigned int u = __float_as_uint(fmaf(acc[4 * g + q], 0.125f, 0.75f)); \
            unsigned int key = ((u >> 3) << 12) | (unsigned int)(kc - (8 * g + q)); \
            ins12m(lk, key); \
        } \
    } }
// diagonal-chunk variant: zero the self column
#define SCAN16D { \
    int c0 = cbase + c * 32 + 4 * lh; \
    int selfslot = r - c0; \
    int kc = 4095 - c0; \
    _Pragma("unroll") \
    for (int g = 0; g < 4; ++g) { \
        _Pragma("unroll") \
        for (int q = 0; q < 4; ++q) { \
            unsigned int u = __float_as_uint(fmaf(acc[4 * g + q], 0.125f, 0.75f)); \
            unsigned int key = ((u >> 3) << 12) | (unsigned int)(kc - (8 * g + q)); \
            key = (8 * g + q == selfslot) ? 0u : key; \
            ins12m(lk, key); \
        } \
    } }

// ---------------- MFMA sim + branchless packed-u32 top-12 ----------
// grid 2800: img(16) x rowblk(25) x seventh(7). 4 waves x 32 rows = 128 rows.
// K-split double buffer (2x12KB); occupancy 5 blocks/CU (20 waves).
// Packed key: fmaf(v,0.125,0.75) in [0.625,0.875] -> one exponent for |v|<2
// -> uint-monotone mantissa; key = mant[22:3]<<12 | (4095-col).
// Partner merge snapshots before insert (round-7 lesson).
__global__ __launch_bounds__(256, 5) void k_simmfma(const unsigned short* __restrict__ xs,
        unsigned int* __restrict__ topk) {
    __shared__ __align__(1024) char SMEM[24576];
    int bid = blockIdx.x;
    int img = bid & 15;
    int rest = bid >> 4;            // 0..174
    int rb = rest / NSEV;           // 0..24
    int sv = rest - rb * NSEV;      // 0..6
    int t = threadIdx.x;
    int w = t >> 6, lane = t & 63;
    int l31 = lane & 31, lh = lane >> 5;
    const char* xsi = (const char*)(xs + (size_t)img * N_ * 384);

    int r = rb * 128 + w * 32 + l31;
    bool valid = r < N_;
    int rl = valid ? r : (N_ - 1);
    bf16x8 bfrag[24];
    {
        const char* rp = xsi + (size_t)rl * 768 + lh * 16;
        #pragma unroll
        for (int ks = 0; ks < 24; ++ks)
            bfrag[ks] = *(const bf16x8*)(rp + ks * 32);
    }
    unsigned int lk[12];
    #pragma unroll
    for (int k = 0; k < 12; ++k) lk[k] = 0u;

    int cbase = sv * SEVCOLS;
    int c_self = rb * 4 + w - sv * 14;   // wave-uniform diag chunk (may be out of [0,14))

    STAGEHALF(SMEM, xsi, cbase, 0, 3)
    __syncthreads();

    for (int c = 0; c < 14; ++c) {
        STAGEHALF(SMEM + 12288, xsi, cbase + c * 32, 1, 3)
        f32x16 acc;
        #pragma unroll
        for (int i = 0; i < 16; ++i) acc[i] = 0.f;
        {
            const char* rp = SMEM + lh * 512 + l31 * 16;
            __builtin_amdgcn_s_setprio(1);
            #pragma unroll
            for (int ks = 0; ks < 12; ++ks) {
                bf16x8 af = *(const bf16x8*)(rp + ks * 1024);
                acc = __builtin_amdgcn_mfma_f32_32x32x16_bf16(af, bfrag[ks], acc, 0, 0, 0);
            }
            __builtin_amdgcn_s_setprio(0);
        }
        __syncthreads();
        if (c < 13) { STAGEHALF(SMEM, xsi, cbase + (c + 1) * 32, 0, 3) }
        {
            const char* rp = SMEM + 12288 + lh * 512 + l31 * 16;
            __builtin_amdgcn_s_setprio(1);
            #pragma unroll
            for (int ks = 0; ks < 12; ++ks) {
                bf16x8 af = *(const bf16x8*)(rp + ks * 1024);
                acc = __builtin_amdgcn_mfma_f32_32x32x16_bf16(af, bfrag[12 + ks], acc, 0, 0, 0);
            }
            __builtin_amdgcn_s_setprio(0);
        }
        if (valid) {
            if (c == c_self) SCAN16D
            else             SCAN16
        }
        __syncthreads();
    }
    // merge partner lane: snapshot ALL partner keys first, then insert
    unsigned int pk[12];
    #pragma unroll
    for (int j = 0; j < 12; ++j)
        pk[j] = (unsigned int)__shfl_xor((int)lk[j], 32, 64);
    #pragma unroll
    for (int j = 0; j < 12; ++j) ins12m(lk, pk[j]);
    if (valid && lh == 0) {
        unsigned int* op = topk + ((size_t)sv * BN_ + (size_t)img * N_ + r) * 12;
        #pragma unroll
        for (int k = 0; k < 12; ++k) op[k] = lk[k];
    }
}

// ---------------- patch head via MFMA (K-split 24KB, occupancy 4) -------------
__global__ __launch_bounds__(256, 4) void k_patchmfma(const unsigned short* __restrict__ xs,
        const unsigned short* __restrict__ wsc, const float* __restrict__ norms,
        const float* __restrict__ cb, float* __restrict__ outp) {
    __shared__ __align__(1024) char SMEM[24576];
    int bid = blockIdx.x;
    int img = bid & 15;
    int n0 = (bid >> 4) * 64;
    int t = threadIdx.x;
    int w = t >> 6, lane = t & 63;
    int l31 = lane & 31, lh = lane >> 5;
    const char* xsi = (const char*)(xs + (size_t)img * N_ * 384);
    int ch = w * 32 + l31;
    bf16x8 bfrag[24];
    {
        const char* wp = (const char*)wsc + (size_t)ch * 768 + lh * 16;
        #pragma unroll
        for (int ks = 0; ks < 24; ++ks)
            bfrag[ks] = *(const bf16x8*)(wp + ks * 32);
    }
    float bias = (ch < NC_) ? cb[ch] : 0.f;
    STAGEHALF(SMEM, xsi, n0, 0, 3)
    __syncthreads();
    for (int c = 0; c < 2; ++c) {
        STAGEHALF(SMEM + 12288, xsi, n0 + c * 32, 1, 3)
        f32x16 acc;
        #pragma unroll
        for (int i = 0; i < 16; ++i) acc[i] = 0.f;
        {
            const char* rp = SMEM + lh * 512 + l31 * 16;
            #pragma unroll
            for (int ks = 0; ks < 12; ++ks) {
                bf16x8 af = *(const bf16x8*)(rp + ks * 1024);
                acc = __builtin_amdgcn_mfma_f32_32x32x16_bf16(af, bfrag[ks], acc, 0, 0, 0);
            }
        }
        __syncthreads();
        if (c == 0) { STAGEHALF(SMEM, xsi, n0 + 32, 0, 3) }
        {
            const char* rp = SMEM + 12288 + lh * 512 + l31 * 16;
            #pragma unroll
            for (int ks = 0; ks < 12; ++ks) {
                bf16x8 af = *(const bf16x8*)(rp + ks * 1024);
                acc = __builtin_amdgcn_mfma_f32_32x32x16_bf16(af, bfrag[12 + ks], acc, 0, 0, 0);
            }
        }
        if (ch < NC_) {
            int nb = n0 + c * 32 + 4 * lh;
            float* op = outp + ((size_t)(img * NC_ + ch)) * N_ + nb;
            const float* npv = norms + (size_t)img * N_ + nb;
            #pragma unroll
            for (int g = 0; g < 4; ++g) {
                float4 nv = *(const float4*)(npv + 8 * g);
                float4 o;
                o.x = acc[4 * g + 0] * nv.x + bias;
                o.y = acc[4 * g + 1] * nv.y + bias;
                o.z = acc[4 * g + 2] * nv.z + bias;
                o.w = acc[4 * g + 3] * nv.w + bias;
                *(float4*)(op + 8 * g) = o;
            }
        }
        __syncthreads();
    }
}

// ---------------- GNN linear+relu via MFMA: h = relu(XS @ WSG^T + b) ---------
__global__ __launch_bounds__(384, 3) void k_gnnmfma(const unsigned short* __restrict__ xs,
        const unsigned short* __restrict__ wsg, const float* __restrict__ gbias,
        float* __restrict__ h) {
    __shared__ __align__(1024) char SMEM[49152];
    int n0 = blockIdx.x * 128;
    int t = threadIdx.x;
    int w = t / 64, lane = t & 63;
    int l31 = lane & 31, lh = lane >> 5;
    int j = w * 32 + l31;
    bf16x8 bfrag[24];
    {
        const char* wp = (const char*)wsg + (size_t)j * 768 + lh * 16;
        #pragma unroll
        for (int ks = 0; ks < 24; ++ks)
            bfrag[ks] = *(const bf16x8*)(wp + ks * 32);
    }
    float bj = gbias[j];
    STAGE32(SMEM, (const char*)xs + (size_t)(n0 + l31) * 768 + w * 128 + lh * 16, 4);
    __syncthreads();
    for (int c = 0; c < 4; ++c) {
        char* cur = SMEM + (c & 1) * 24576;
        if (c < 3) {
            char* dst = SMEM + ((c & 1) ^ 1) * 24576;
            STAGE32(dst, (const char*)xs + (size_t)(n0 + (c + 1) * 32 + l31) * 768 + w * 128 + lh * 16, 4);
        }
        f32x16 acc;
        #pragma unroll
        for (int i = 0; i < 16; ++i) acc[i] = 0.f;
        const char* rp = cur + lh * 512 + l31 * 16;
        #pragma unroll
        for (int ks = 0; ks < 24; ++ks) {
            bf16x8 af = *(const bf16x8*)(rp + ks * 1024);
            acc = __builtin_amdgcn_mfma_f32_32x32x16_bf16(af, bfrag[ks], acc, 0, 0, 0);
        }
        int nb = n0 + c * 32 + 4 * lh;
        #pragma unroll
        for (int g = 0; g < 4; ++g)
            #pragma unroll
            for (int q = 0; q < 4; ++q)
                h[(size_t)(nb + 8 * g + q) * C_ + j] = fmaxf(acc[4 * g + q] + bj, 0.f);
        __syncthreads();
    }
}

// ---------------- merge 7 per-seventh packed lists -> top-12 candidates -------
__global__ __launch_bounds__(256) void k_merge2(const unsigned int* __restrict__ topk,
        int* __restrict__ nbr12) {
    int row = blockIdx.x * 256 + threadIdx.x;      // 50176
    unsigned int lk[12];
    const unsigned int* p0 = topk + (size_t)row * 12;
    #pragma unroll
    for (int k = 0; k < 12; ++k) lk[k] = p0[k];
    #pragma unroll
    for (int h = 1; h < NSEV; ++h) {
        const unsigned int* p1 = topk + ((size_t)h * BN_ + row) * 12;
        #pragma unroll
        for (int j = 0; j < 12; ++j) ins12m(lk, p1[j]);
    }
    int gb = (row / N_) * N_;
    int* np = nbr12 + (size_t)row * 12;
    #pragma unroll
    for (int k = 0; k < 12; ++k) np[k] = gb + (4095 - (int)(lk[k] & 0xFFFu));
}

// -------- exact fp32 rescore, cooperative 16-lane (coalesced gathers) ---------
// 16 rows/block; per row: 16 lanes hold 12 channels each (3 float4).
__global__ __launch_bounds__(256) void k_rescore(const float* __restrict__ xn,
        const int* __restrict__ nbr12, int* __restrict__ nbr9) {
    int img = blockIdx.x & 15;
    int sub = blockIdx.x >> 4;                     // 0..195
    int t = threadIdx.x;
    int nl = t >> 4, l16 = t & 15;
    int row = img * N_ + sub * 16 + nl;
    const float4* xa = (const float4*)(xn + (size_t)row * C_) + l16;
    float4 a0 = xa[0], a1 = xa[16], a2 = xa[32];
    const int* np12 = nbr12 + (size_t)row * 12;
    float d[12]; int ci[12];
    #pragma unroll
    for (int j = 0; j < 12; ++j) {
        int cand = np12[j];                        // wave-uniform per 16-group
        ci[j] = cand;
        const float4* xb = (const float4*)(xn + (size_t)cand * C_) + l16;
        float4 b0 = xb[0], b1 = xb[16], b2 = xb[32];
        float s = a0.x*b0.x + a0.y*b0.y + a0.z*b0.z + a0.w*b0.w
                + a1.x*b1.x + a1.y*b1.y + a1.z*b1.z + a1.w*b1.w
                + a2.x*b2.x + a2.y*b2.y + a2.z*b2.z + a2.w*b2.w;
        s += __shfl_xor(s, 1, 64);
        s += __shfl_xor(s, 2, 64);
        s += __shfl_xor(s, 4, 64);
        s += __shfl_xor(s, 8, 64);
        d[j] = (cand != row) ? s : -1e30f;
    }
    float lv[9]; int li[9];
    #pragma unroll
    for (int k = 0; k < 9; ++k) { lv[k] = -1e30f; li[k] = 0x7fffffff; }
    #pragma unroll
    for (int j = 0; j < 12; ++j) ins_lex<9>(lv, li, d[j], ci[j]);
    if (l16 == 0) {
        int* np = nbr9 + (size_t)row * 9;
        #pragma unroll
        for (int k = 0; k < 9; ++k) np[k] = li[k];
    }
}

// -------- edge attention + aggregation + pool partial (16 lanes/node) ---------
__global__ __launch_bounds__(256) void k_edge(const float* __restrict__ h,
        const int* __restrict__ nbr, float* __restrict__ eatt,
        float* __restrict__ gparte) {
    __shared__ float ps[4][C_];
    int img = blockIdx.x & 15;
    int sub = blockIdx.x >> 4;                     // 0..195
    int t = threadIdx.x;
    int wv = t >> 6;
    int nl = t >> 4;                               // node-local 0..15
    int l16 = t & 15;
    int node = img * N_ + sub * 16 + nl;
    const float4* hc = (const float4*)(h + (size_t)node * C_) + l16;
    float4 c0 = hc[0], c1 = hc[16], c2 = hc[32];
    float4 m0 = make_float4(0,0,0,0), m1 = make_float4(0,0,0,0), m2 = make_float4(0,0,0,0);
    const int* np_ = nbr + (size_t)node * K_;
    float* ep = eatt + (size_t)node * K_;
    #pragma unroll
    for (int k = 0; k < K_; ++k) {
        int src = np_[k];
        const float4* hs = (const float4*)(h + (size_t)src * C_) + l16;
        float4 s0 = hs[0], s1 = hs[16], s2 = hs[32];
        float d = s0.x*c0.x + s0.y*c0.y + s0.z*c0.z + s0.w*c0.w
                + s1.x*c1.x + s1.y*c1.y + s1.z*c1.z + s1.w*c1.w
                + s2.x*c2.x + s2.y*c2.y + s2.z*c2.z + s2.w*c2.w;
        d += __shfl_xor(d, 1, 64);
        d += __shfl_xor(d, 2, 64);
        d += __shfl_xor(d, 4, 64);
        d += __shfl_xor(d, 8, 64);
        if (l16 == 0) ep[k] = 1.0f / (1.0f + expf(-d));
        m0.x += s0.x; m0.y += s0.y; m0.z += s0.z; m0.w += s0.w;
        m1.x += s1.x; m1.y += s1.y; m1.z += s1.z; m1.w += s1.w;
        m2.x += s2.x; m2.y += s2.y; m2.z += s2.z; m2.w += s2.w;
    }
    const float r9 = 1.0f / 9.0f;
    float v[12];
    v[0] = c0.x + m0.x * r9; v[1]  = c0.y + m0.y * r9;
    v[2] = c0.z + m0.z * r9; v[3]  = c0.w + m0.w * r9;
    v[4] = c1.x + m1.x * r9; v[5]  = c1.y + m1.y * r9;
    v[6] = c1.z + m1.z * r9; v[7]  = c1.w + m1.w * r9;
    v[8] = c2.x + m2.x * r9; v[9]  = c2.y + m2.y * r9;
    v[10] = c2.z + m2.z * r9; v[11] = c2.w + m2.w * r9;
    #pragma unroll
    for (int e = 0; e < 12; ++e) {
        v[e] += __shfl_xor(v[e], 16, 64);
        v[e] += __shfl_xor(v[e], 32, 64);
    }
    if ((t & 63) < 16) {
        #pragma unroll
        for (int j = 0; j < 3; ++j)
            #pragma unroll
            for (int e = 0; e < 4; ++e)
                ps[wv][j * 64 + l16 * 4 + e] = v[j * 4 + e];
    }
    __syncthreads();
    if (t < C_)
        gparte[(size_t)blockIdx.x * C_ + t] =
            (ps[0][t] + ps[1][t]) + (ps[2][t] + ps[3][t]);
}

// ---------------- pool partials: 196 blocks/image -> 4 segments ---------------
__global__ __launch_bounds__(192) void k_gred(const float* __restrict__ gparte,
        float* __restrict__ gpart) {
    int b = blockIdx.x >> 2, s = blockIdx.x & 3;   // grid 64
    int oc = threadIdx.x;
    float acc = 0.f;
    for (int sub = s * 49; sub < (s + 1) * 49; ++sub)
        acc += gparte[((size_t)(sub * 16 + b)) * C_ + oc];
    gpart[(size_t)(b * 4 + s) * C_ + oc] = acc;
}

// ---------------- MLP stage 1: z = gs@w1+b1 -> BN -> GELU -> zs ---------------
__global__ __launch_bounds__(256) void k_mlp1(const float* __restrict__ gpart,
        const float* __restrict__ w1, const float* __restrict__ b1,
        const float* __restrict__ gam, const float* __restrict__ bet,
        float* __restrict__ zs) {
    __shared__ float gs[B_ * C_];
    int t = threadIdx.x;
    int j = blockIdx.x * 256 + t;                  // 0..1023
    for (int f = t; f < B_ * C_; f += 256) {
        int b = f / C_, oc = f - b * C_;
        float a = 0.f;
        #pragma unroll
        for (int s = 0; s < 4; ++s) a += gpart[((size_t)(b * 4 + s)) * C_ + oc];
        gs[f] = a;
    }
    __syncthreads();
    float z[16];
    #pragma unroll
    for (int i = 0; i < 16; ++i) z[i] = b1[j];
    for (int c = 0; c < C_; ++c) {
        float w = w1[(size_t)c * PD_ + j];
        #pragma unroll
        for (int i = 0; i < 16; ++i) z[i] += gs[i * C_ + c] * w;
    }
    float mu = 0.f;
    #pragma unroll
    for (int i = 0; i < 16; ++i) mu += z[i];
    mu *= (1.0f / 16.0f);
    float var = 0.f;
    #pragma unroll
    for (int i = 0; i < 16; ++i) { float d = z[i] - mu; var += d * d; }
    var *= (1.0f / 16.0f);
    float sc = (1.0f / sqrtf(var + 1e-5f)) * gam[j];
    float bt = bet[j];
    #pragma unroll
    for (int i = 0; i < 16; ++i) {
        float zh = (z[i] - mu) * sc + bt;
        zs[(size_t)i * PD_ + j] = 0.5f * zh * (1.0f + erff(zh * 0.70710678118654752f));
    }
}

// ---------------- MLP stage 2: pred = zs @ w2 + b2 (w2 pre-transposed) --------
__global__ __launch_bounds__(64) void k_mlp2(const float* __restrict__ zs,
        const float* __restrict__ w2t, const float* __restrict__ b2,
        float* __restrict__ pred) {
    int i = blockIdx.x / NC_, jj = blockIdx.x - i * NC_;
    int lane = threadIdx.x;
    const float* zr = zs + (size_t)i * PD_;
    const float* wr = w2t + (size_t)jj * PD_;
    float a = 0.f;
    #pragma unroll
    for (int k = 0; k < 16; ++k) a += zr[lane + 64 * k] * wr[lane + 64 * k];
    a += __shfl_xor(a, 1, 64);  a += __shfl_xor(a, 2, 64);
    a += __shfl_xor(a, 4, 64);  a += __shfl_xor(a, 8, 64);
    a += __shfl_xor(a, 16, 64); a += __shfl_xor(a, 32, 64);
    if (lane == 0) pred[i * NC_ + jj] = a + b2[jj];
}

extern "C" void kernel_launch(void* const* d_in, const int* in_sizes, int n_in,
                              void* d_out, int out_size, void* d_ws, size_t ws_size,
                              hipStream_t stream) {
    const float* img    = (const float*)d_in[0];
    const float* conv_w = (const float*)d_in[1];
    const float* conv_b = (const float*)d_in[2];
    const float* gnn_w  = (const float*)d_in[3];
    const float* gnn_b  = (const float*)d_in[4];
    const float* w1     = (const float*)d_in[5];
    const float* b1     = (const float*)d_in[6];
    const float* bng    = (const float*)d_in[7];
    const float* bnb    = (const float*)d_in[8];
    const float* w2     = (const float*)d_in[9];
    const float* b2     = (const float*)d_in[10];
    float* out = (float*)d_out;

    float* XN            = (float*)d_ws;                        // BN*192 f32
    unsigned short* XS   = (unsigned short*)(XN + (size_t)BN_ * C_);  // BN*384
    unsigned int* TOPK   = (unsigned int*)(XS + (size_t)BN_ * 384);   // 7*BN*12
    int*   NBR12         = (int*)(TOPK + (size_t)NSEV * BN_ * 12);
    int*   NBR9          = NBR12 + (size_t)BN_ * 12;
    float* NORMS         = (float*)(NBR9 + (size_t)BN_ * K_);   // BN
    unsigned short* WSC  = (unsigned short*)(NORMS + BN_);      // 128*384
    unsigned short* WSG  = WSC + (size_t)128 * 384;             // 192*384
    float* GPART         = (float*)(WSG + (size_t)192 * 384);   // 64*C
    float* W2T           = GPART + (size_t)128 * C_;            // 100*1024
    float* Hh            = XN;            // reuse: XN dead after k_rescore
    float* GPARTE        = (float*)TOPK;  // reuse: TOPK dead after k_merge2
    float* ZS            = (float*)NBR12; // reuse: NBR12 dead after k_rescore

    k_normalize<<<784, 256, 0, stream>>>(img, XN, XS, NORMS);
    k_wsplit   <<<640, 256, 0, stream>>>(conv_w, gnn_w, w2, WSC, WSG, W2T);
    k_patchmfma<<<784, 256, 0, stream>>>(XS, WSC, NORMS, conv_b, out + OUT_PP);
    k_simmfma  <<<2800, 256, 0, stream>>>(XS, TOPK);
    k_merge2   <<<196, 256, 0, stream>>>(TOPK, NBR12);
    k_rescore  <<<3136, 256, 0, stream>>>(XN, NBR12, NBR9);
    k_gnnmfma  <<<392, 384, 0, stream>>>(XS, WSG, gnn_b, Hh);
    k_edge     <<<3136, 256, 0, stream>>>(Hh, NBR9, out + OUT_EATT, GPARTE);
    k_gred     <<<64, 192, 0, stream>>>(GPARTE, GPART);
    k_mlp1     <<<4, 256, 0, stream>>>(GPART, w1, b1, bng, bnb, ZS);
    k_mlp2     <<<1600, 64, 0, stream>>>(ZS, W2T, b2, out);
}

// Round 13
// 477.994 us; speedup vs baseline: 1.3758x; 1.3758x over previous
//
#include <hip/hip_runtime.h>
#include <math.h>

#define B_  16
#define C_  192
#define N_  3136
#define BN_ 50176
#define K_  9
#define NC_ 100
#define PD_ 1024
#define NSEV 7
#define SEVCOLS 448

#define OUT_EATT 1600
#define OUT_PP   453184

typedef short bf16x8 __attribute__((ext_vector_type(8)));
typedef float f32x16 __attribute__((ext_vector_type(16)));

__device__ __forceinline__ unsigned int umaxu(unsigned int a, unsigned int b) { return a > b ? a : b; }
__device__ __forceinline__ unsigned int med3u(unsigned int a, unsigned int b, unsigned int c) {
    unsigned int d;
    asm("v_med3_u32 %0, %1, %2, %3" : "=v"(d) : "v"(a), "v"(b), "v"(c));
    return d;
}
// insert key into sorted-desc lk[12]: L'[0]=max(L0,x), L'[k]=med3(L[k-1],L[k],x)
__device__ __forceinline__ void ins12m(unsigned int (&lk)[12], unsigned int key) {
    unsigned int nk[12];
    nk[0] = umaxu(lk[0], key);
    #pragma unroll
    for (int k = 1; k < 12; ++k) nk[k] = med3u(lk[k - 1], lk[k], key);
    #pragma unroll
    for (int k = 0; k < 12; ++k) lk[k] = nk[k];
}

// lexicographic (val desc, idx asc) insertion (rescore)
template<int NL>
__device__ inline void ins_lex(float (&lv)[NL], int (&li)[NL], float v, int vi) {
    if (v > lv[NL-1] || (v == lv[NL-1] && vi < li[NL-1])) {
        #pragma unroll
        for (int k = 0; k < NL; ++k) {
            bool p = (v > lv[k]) || (v == lv[k] && vi < li[k]);
            float fv = p ? lv[k] : v; int fi = p ? li[k] : vi;
            lv[k] = p ? v : lv[k];    li[k] = p ? vi : li[k];
            v = fv; vi = fi;
        }
    }
}

__device__ inline unsigned int bf16_rne(unsigned int u) {
    return (u + 0x7fffu + ((u >> 16) & 1u)) & 0xffff0000u;
}

// ---------------- normalize: [B,C,N] -> XN f32, XS bf16 hi|lo split, NORMS ----
__global__ __launch_bounds__(256) void k_normalize(const float* __restrict__ in,
        float* __restrict__ xn, unsigned short* __restrict__ xsn,
        float* __restrict__ norms) {
    __shared__ float tile[C_][65];
    __shared__ float part[4][64];
    __shared__ float rnorm_s[64];
    int b = blockIdx.x & 15;
    int n0 = (blockIdx.x >> 4) * 64;
    int t = threadIdx.x;
    for (int f = t; f < C_ * 64; f += 256) {
        int c = f >> 6, n = f & 63;
        tile[c][n] = in[((size_t)b * C_ + c) * N_ + n0 + n];
    }
    __syncthreads();
    {
        int n = t & 63, qq = t >> 6;
        float s = 0.f;
        #pragma unroll
        for (int i = 0; i < 48; ++i) { float v = tile[qq * 48 + i][n]; s += v * v; }
        part[qq][n] = s;
    }
    __syncthreads();
    if (t < 64) {
        float tot = part[0][t] + part[1][t] + part[2][t] + part[3][t];
        float nrm = fmaxf(sqrtf(tot), 1e-12f);
        norms[(size_t)b * N_ + n0 + t] = nrm;
        rnorm_s[t] = 1.0f / nrm;
    }
    __syncthreads();
    for (int f = t; f < 64 * 96; f += 256) {
        int n = f / 96, cp = f - n * 96;
        int c = cp * 2;
        float r = rnorm_s[n];
        float v0 = tile[c][n] * r;
        float v1 = tile[c + 1][n] * r;
        size_t row = (size_t)b * N_ + n0 + n;
        *(float2*)(xn + row * C_ + c) = make_float2(v0, v1);
        unsigned int h0 = bf16_rne(__float_as_uint(v0));
        unsigned int h1 = bf16_rne(__float_as_uint(v1));
        unsigned int l0 = bf16_rne(__float_as_uint(v0 - __uint_as_float(h0)));
        unsigned int l1 = bf16_rne(__float_as_uint(v1 - __uint_as_float(h1)));
        unsigned int* xr = (unsigned int*)(xsn + row * 384);
        xr[cp]      = (h0 >> 16) | (h1 & 0xffff0000u);
        xr[96 + cp] = (l0 >> 16) | (l1 & 0xffff0000u);
    }
}

// ---------------- split conv_w / gnn_w to bf16 hi|lo; transpose w2 ------------
__global__ __launch_bounds__(256) void k_wsplit(const float* __restrict__ cw,
        const float* __restrict__ gw, const float* __restrict__ w2,
        unsigned short* __restrict__ wsc, unsigned short* __restrict__ wsg,
        float* __restrict__ w2t) {
    int id = blockIdx.x * 256 + threadIdx.x;   // 640*256 = 163840
    if (id < 128 * 192) {
        int k = id / 192, c = id - k * 192;
        float v = (k < 100) ? cw[k * 192 + c] : 0.f;
        unsigned int h = bf16_rne(__float_as_uint(v));
        wsc[(size_t)k * 384 + c] = (unsigned short)(h >> 16);
        wsc[(size_t)k * 384 + 192 + c] =
            (unsigned short)(bf16_rne(__float_as_uint(v - __uint_as_float(h))) >> 16);
    } else if (id < 61440) {
        int e = id - 128 * 192;
        int cc = e / 192, j = e - cc * 192;
        float v = gw[cc * 192 + j];
        unsigned int h = bf16_rne(__float_as_uint(v));
        wsg[(size_t)j * 384 + cc] = (unsigned short)(h >> 16);
        wsg[(size_t)j * 384 + 192 + cc] =
            (unsigned short)(bf16_rne(__float_as_uint(v - __uint_as_float(h))) >> 16);
    } else {
        int e2 = id - 61440;                   // 0..102399
        int jj = e2 >> 10, k = e2 & 1023;
        w2t[(size_t)jj * PD_ + k] = w2[(size_t)k * NC_ + jj];
    }
}

// stage one 32-col chunk via global_load_lds; NLW = glds per wave
#define STAGE32(DST, SRCBASE, NLW) { \
    const char* s_ = (SRCBASE); \
    _Pragma("unroll") \
    for (int q_ = 0; q_ < NLW; ++q_) \
        __builtin_amdgcn_global_load_lds( \
            (const __attribute__((address_space(1))) unsigned int*)(s_ + q_ * 32), \
            (__attribute__((address_space(3))) unsigned int*)((DST) + (w * NLW + q_) * 1024), 16, 0, 0); }

// stage one K-HALF of a 32-col chunk (12KB); NLW glds per wave (NLW*waves=12)
#define STAGEHALF(DST, BASE, COLB, KH, NLW) { \
    _Pragma("unroll") \
    for (int q_ = 0; q_ < NLW; ++q_) { \
        const char* s_ = (BASE) + (size_t)((COLB) + l31) * 768 + (KH) * 384 + (w * (NLW) + q_) * 32 + lh * 16; \
        __builtin_amdgcn_global_load_lds( \
            (const __attribute__((address_space(1))) unsigned int*)s_, \
            (__attribute__((address_space(3))) unsigned int*)((DST) + (w * (NLW) + q_) * 1024), 16, 0, 0); } }

// 16-candidate packed-key scan into lk[12] (med3); off-diagonal chunk (no self test)
#define SCAN16 { \
    int c0 = cbase + c * 32 + 4 * lh; \
    int kc = 4095 - c0; \
    _Pragma("unroll") \
    for (int g = 0; g < 4; ++g) { \
        _Pragma("unroll") \
        for (int q = 0; q < 4; ++q) { \
            unsigned int u = __float_as_uint(fmaf(acc[4 * g + q], 0.125f, 0.75f)); \
            unsigned int key = ((u >> 3) << 12) | (unsigned int)(kc - (8 * g + q)); \
            ins12m(lk, key); \
        } \
    } }
// diagonal-chunk variant: zero the self column
#define SCAN16D { \
    int c0 = cbase + c * 32 + 4 * lh; \
    int selfslot = r - c0; \
    int kc = 4095 - c0; \
    _Pragma("unroll") \
    for (int g = 0; g < 4; ++g) { \
        _Pragma("unroll") \
        for (int q = 0; q < 4; ++q) { \
            unsigned int u = __float_as_uint(fmaf(acc[4 * g + q], 0.125f, 0.75f)); \
            unsigned int key = ((u >> 3) << 12) | (unsigned int)(kc - (8 * g + q)); \
            key = (8 * g + q == selfslot) ? 0u : key; \
            ins12m(lk, key); \
        } \
    } }

// ---------------- MFMA sim + branchless packed-u32 top-12 ----------
// grid 2800: img(16) x rowblk(25) x seventh(7). 4 waves x 32 rows = 128 rows.
// K-split double buffer (2x12KB); occupancy 4 blocks/CU (16 waves, VGPR cap
// 128 >= 80 actual -- (256,5) capped VGPR at ~81 and SPILLED bfrag: round-12
// regression, FETCH 8x, WRITE=scratch. Do not exceed 4.)
// Packed key: fmaf(v,0.125,0.75) in [0.625,0.875] -> one exponent for |v|<2
// -> uint-monotone mantissa; key = mant[22:3]<<12 | (4095-col).
// Partner merge snapshots before insert (round-7 lesson).
__global__ __launch_bounds__(256, 4) void k_simmfma(const unsigned short* __restrict__ xs,
        unsigned int* __restrict__ topk) {
    __shared__ __align__(1024) char SMEM[24576];
    int bid = blockIdx.x;
    int img = bid & 15;
    int rest = bid >> 4;            // 0..174
    int rb = rest / NSEV;           // 0..24
    int sv = rest - rb * NSEV;      // 0..6
    int t = threadIdx.x;
    int w = t >> 6, lane = t & 63;
    int l31 = lane & 31, lh = lane >> 5;
    const char* xsi = (const char*)(xs + (size_t)img * N_ * 384);

    int r = rb * 128 + w * 32 + l31;
    bool valid = r < N_;
    int rl = valid ? r : (N_ - 1);
    bf16x8 bfrag[24];
    {
        const char* rp = xsi + (size_t)rl * 768 + lh * 16;
        #pragma unroll
        for (int ks = 0; ks < 24; ++ks)
            bfrag[ks] = *(const bf16x8*)(rp + ks * 32);
    }
    unsigned int lk[12];
    #pragma unroll
    for (int k = 0; k < 12; ++k) lk[k] = 0u;

    int cbase = sv * SEVCOLS;
    int c_self = rb * 4 + w - sv * 14;   // wave-uniform diag chunk (may be out of [0,14))

    STAGEHALF(SMEM, xsi, cbase, 0, 3)
    __syncthreads();

    for (int c = 0; c < 14; ++c) {
        STAGEHALF(SMEM + 12288, xsi, cbase + c * 32, 1, 3)
        f32x16 acc;
        #pragma unroll
        for (int i = 0; i < 16; ++i) acc[i] = 0.f;
        {
            const char* rp = SMEM + lh * 512 + l31 * 16;
            __builtin_amdgcn_s_setprio(1);
            #pragma unroll
            for (int ks = 0; ks < 12; ++ks) {
                bf16x8 af = *(const bf16x8*)(rp + ks * 1024);
                acc = __builtin_amdgcn_mfma_f32_32x32x16_bf16(af, bfrag[ks], acc, 0, 0, 0);
            }
            __builtin_amdgcn_s_setprio(0);
        }
        __syncthreads();
        if (c < 13) { STAGEHALF(SMEM, xsi, cbase + (c + 1) * 32, 0, 3) }
        {
            const char* rp = SMEM + 12288 + lh * 512 + l31 * 16;
            __builtin_amdgcn_s_setprio(1);
            #pragma unroll
            for (int ks = 0; ks < 12; ++ks) {
                bf16x8 af = *(const bf16x8*)(rp + ks * 1024);
                acc = __builtin_amdgcn_mfma_f32_32x32x16_bf16(af, bfrag[12 + ks], acc, 0, 0, 0);
            }
            __builtin_amdgcn_s_setprio(0);
        }
        if (valid) {
            if (c == c_self) SCAN16D
            else             SCAN16
        }
        __syncthreads();
    }
    // merge partner lane: snapshot ALL partner keys first, then insert
    unsigned int pk[12];
    #pragma unroll
    for (int j = 0; j < 12; ++j)
        pk[j] = (unsigned int)__shfl_xor((int)lk[j], 32, 64);
    #pragma unroll
    for (int j = 0; j < 12; ++j) ins12m(lk, pk[j]);
    if (valid && lh == 0) {
        unsigned int* op = topk + ((size_t)sv * BN_ + (size_t)img * N_ + r) * 12;
        #pragma unroll
        for (int k = 0; k < 12; ++k) op[k] = lk[k];
    }
}

// ---------------- patch head via MFMA (K-split 24KB, occupancy 4) -------------
__global__ __launch_bounds__(256, 4) void k_patchmfma(const unsigned short* __restrict__ xs,
        const unsigned short* __restrict__ wsc, const float* __restrict__ norms,
        const float* __restrict__ cb, float* __restrict__ outp) {
    __shared__ __align__(1024) char SMEM[24576];
    int bid = blockIdx.x;
    int img = bid & 15;
    int n0 = (bid >> 4) * 64;
    int t = threadIdx.x;
    int w = t >> 6, lane = t & 63;
    int l31 = lane & 31, lh = lane >> 5;
    const char* xsi = (const char*)(xs + (size_t)img * N_ * 384);
    int ch = w * 32 + l31;
    bf16x8 bfrag[24];
    {
        const char* wp = (const char*)wsc + (size_t)ch * 768 + lh * 16;
        #pragma unroll
        for (int ks = 0; ks < 24; ++ks)
            bfrag[ks] = *(const bf16x8*)(wp + ks * 32);
    }
    float bias = (ch < NC_) ? cb[ch] : 0.f;
    STAGEHALF(SMEM, xsi, n0, 0, 3)
    __syncthreads();
    for (int c = 0; c < 2; ++c) {
        STAGEHALF(SMEM + 12288, xsi, n0 + c * 32, 1, 3)
        f32x16 acc;
        #pragma unroll
        for (int i = 0; i < 16; ++i) acc[i] = 0.f;
        {
            const char* rp = SMEM + lh * 512 + l31 * 16;
            #pragma unroll
            for (int ks = 0; ks < 12; ++ks) {
                bf16x8 af = *(const bf16x8*)(rp + ks * 1024);
                acc = __builtin_amdgcn_mfma_f32_32x32x16_bf16(af, bfrag[ks], acc, 0, 0, 0);
            }
        }
        __syncthreads();
        if (c == 0) { STAGEHALF(SMEM, xsi, n0 + 32, 0, 3) }
        {
            const char* rp = SMEM + 12288 + lh * 512 + l31 * 16;
            #pragma unroll
            for (int ks = 0; ks < 12; ++ks) {
                bf16x8 af = *(const bf16x8*)(rp + ks * 1024);
                acc = __builtin_amdgcn_mfma_f32_32x32x16_bf16(af, bfrag[12 + ks], acc, 0, 0, 0);
            }
        }
        if (ch < NC_) {
            int nb = n0 + c * 32 + 4 * lh;
            float* op = outp + ((size_t)(img * NC_ + ch)) * N_ + nb;
            const float* npv = norms + (size_t)img * N_ + nb;
            #pragma unroll
            for (int g = 0; g < 4; ++g) {
                float4 nv = *(const float4*)(npv + 8 * g);
                float4 o;
                o.x = acc[4 * g + 0] * nv.x + bias;
                o.y = acc[4 * g + 1] * nv.y + bias;
                o.z = acc[4 * g + 2] * nv.z + bias;
                o.w = acc[4 * g + 3] * nv.w + bias;
                *(float4*)(op + 8 * g) = o;
            }
        }
        __syncthreads();
    }
}

// ---------------- GNN linear+relu via MFMA: h = relu(XS @ WSG^T + b) ---------
__global__ __launch_bounds__(384, 3) void k_gnnmfma(const unsigned short* __restrict__ xs,
        const unsigned short* __restrict__ wsg, const float* __restrict__ gbias,
        float* __restrict__ h) {
    __shared__ __align__(1024) char SMEM[49152];
    int n0 = blockIdx.x * 128;
    int t = threadIdx.x;
    int w = t / 64, lane = t & 63;
    int l31 = lane & 31, lh = lane >> 5;
    int j = w * 32 + l31;
    bf16x8 bfrag[24];
    {
        const char* wp = (const char*)wsg + (size_t)j * 768 + lh * 16;
        #pragma unroll
        for (int ks = 0; ks < 24; ++ks)
            bfrag[ks] = *(const bf16x8*)(wp + ks * 32);
    }
    float bj = gbias[j];
    STAGE32(SMEM, (const char*)xs + (size_t)(n0 + l31) * 768 + w * 128 + lh * 16, 4);
    __syncthreads();
    for (int c = 0; c < 4; ++c) {
        char* cur = SMEM + (c & 1) * 24576;
        if (c < 3) {
            char* dst = SMEM + ((c & 1) ^ 1) * 24576;
            STAGE32(dst, (const char*)xs + (size_t)(n0 + (c + 1) * 32 + l31) * 768 + w * 128 + lh * 16, 4);
        }
        f32x16 acc;
        #pragma unroll
        for (int i = 0; i < 16; ++i) acc[i] = 0.f;
        const char* rp = cur + lh * 512 + l31 * 16;
        #pragma unroll
        for (int ks = 0; ks < 24; ++ks) {
            bf16x8 af = *(const bf16x8*)(rp + ks * 1024);
            acc = __builtin_amdgcn_mfma_f32_32x32x16_bf16(af, bfrag[ks], acc, 0, 0, 0);
        }
        int nb = n0 + c * 32 + 4 * lh;
        #pragma unroll
        for (int g = 0; g < 4; ++g)
            #pragma unroll
            for (int q = 0; q < 4; ++q)
                h[(size_t)(nb + 8 * g + q) * C_ + j] = fmaxf(acc[4 * g + q] + bj, 0.f);
        __syncthreads();
    }
}

// ---------------- merge 7 per-seventh packed lists -> top-12 candidates -------
__global__ __launch_bounds__(256) void k_merge2(const unsigned int* __restrict__ topk,
        int* __restrict__ nbr12) {
    int row = blockIdx.x * 256 + threadIdx.x;      // 50176
    unsigned int lk[12];
    const unsigned int* p0 = topk + (size_t)row * 12;
    #pragma unroll
    for (int k = 0; k < 12; ++k) lk[k] = p0[k];
    #pragma unroll
    for (int h = 1; h < NSEV; ++h) {
        const unsigned int* p1 = topk + ((size_t)h * BN_ + row) * 12;
        #pragma unroll
        for (int j = 0; j < 12; ++j) ins12m(lk, p1[j]);
    }
    int gb = (row / N_) * N_;
    int* np = nbr12 + (size_t)row * 12;
    #pragma unroll
    for (int k = 0; k < 12; ++k) np[k] = gb + (4095 - (int)(lk[k] & 0xFFFu));
}

// -------- exact fp32 rescore, cooperative 16-lane (coalesced gathers) ---------
// 16 rows/block; per row: 16 lanes hold 12 channels each (3 float4).
__global__ __launch_bounds__(256) void k_rescore(const float* __restrict__ xn,
        const int* __restrict__ nbr12, int* __restrict__ nbr9) {
    int img = blockIdx.x & 15;
    int sub = blockIdx.x >> 4;                     // 0..195
    int t = threadIdx.x;
    int nl = t >> 4, l16 = t & 15;
    int row = img * N_ + sub * 16 + nl;
    const float4* xa = (const float4*)(xn + (size_t)row * C_) + l16;
    float4 a0 = xa[0], a1 = xa[16], a2 = xa[32];
    const int* np12 = nbr12 + (size_t)row * 12;
    float d[12]; int ci[12];
    #pragma unroll
    for (int j = 0; j < 12; ++j) {
        int cand = np12[j];                        // wave-uniform per 16-group
        ci[j] = cand;
        const float4* xb = (const float4*)(xn + (size_t)cand * C_) + l16;
        float4 b0 = xb[0], b1 = xb[16], b2 = xb[32];
        float s = a0.x*b0.x + a0.y*b0.y + a0.z*b0.z + a0.w*b0.w
                + a1.x*b1.x + a1.y*b1.y + a1.z*b1.z + a1.w*b1.w
                + a2.x*b2.x + a2.y*b2.y + a2.z*b2.z + a2.w*b2.w;
        s += __shfl_xor(s, 1, 64);
        s += __shfl_xor(s, 2, 64);
        s += __shfl_xor(s, 4, 64);
        s += __shfl_xor(s, 8, 64);
        d[j] = (cand != row) ? s : -1e30f;
    }
    float lv[9]; int li[9];
    #pragma unroll
    for (int k = 0; k < 9; ++k) { lv[k] = -1e30f; li[k] = 0x7fffffff; }
    #pragma unroll
    for (int j = 0; j < 12; ++j) ins_lex<9>(lv, li, d[j], ci[j]);
    if (l16 == 0) {
        int* np = nbr9 + (size_t)row * 9;
        #pragma unroll
        for (int k = 0; k < 9; ++k) np[k] = li[k];
    }
}

// -------- edge attention + aggregation + pool partial (16 lanes/node) ---------
__global__ __launch_bounds__(256) void k_edge(const float* __restrict__ h,
        const int* __restrict__ nbr, float* __restrict__ eatt,
        float* __restrict__ gparte) {
    __shared__ float ps[4][C_];
    int img = blockIdx.x & 15;
    int sub = blockIdx.x >> 4;                     // 0..195
    int t = threadIdx.x;
    int wv = t >> 6;
    int nl = t >> 4;                               // node-local 0..15
    int l16 = t & 15;
    int node = img * N_ + sub * 16 + nl;
    const float4* hc = (const float4*)(h + (size_t)node * C_) + l16;
    float4 c0 = hc[0], c1 = hc[16], c2 = hc[32];
    float4 m0 = make_float4(0,0,0,0), m1 = make_float4(0,0,0,0), m2 = make_float4(0,0,0,0);
    const int* np_ = nbr + (size_t)node * K_;
    float* ep = eatt + (size_t)node * K_;
    #pragma unroll
    for (int k = 0; k < K_; ++k) {
        int src = np_[k];
        const float4* hs = (const float4*)(h + (size_t)src * C_) + l16;
        float4 s0 = hs[0], s1 = hs[16], s2 = hs[32];
        float d = s0.x*c0.x + s0.y*c0.y + s0.z*c0.z + s0.w*c0.w
                + s1.x*c1.x + s1.y*c1.y + s1.z*c1.z + s1.w*c1.w
                + s2.x*c2.x + s2.y*c2.y + s2.z*c2.z + s2.w*c2.w;
        d += __shfl_xor(d, 1, 64);
        d += __shfl_xor(d, 2, 64);
        d += __shfl_xor(d, 4, 64);
        d += __shfl_xor(d, 8, 64);
        if (l16 == 0) ep[k] = 1.0f / (1.0f + expf(-d));
        m0.x += s0.x; m0.y += s0.y; m0.z += s0.z; m0.w += s0.w;
        m1.x += s1.x; m1.y += s1.y; m1.z += s1.z; m1.w += s1.w;
        m2.x += s2.x; m2.y += s2.y; m2.z += s2.z; m2.w += s2.w;
    }
    const float r9 = 1.0f / 9.0f;
    float v[12];
    v[0] = c0.x + m0.x * r9; v[1]  = c0.y + m0.y * r9;
    v[2] = c0.z + m0.z * r9; v[3]  = c0.w + m0.w * r9;
    v[4] = c1.x + m1.x * r9; v[5]  = c1.y + m1.y * r9;
    v[6] = c1.z + m1.z * r9; v[7]  = c1.w + m1.w * r9;
    v[8] = c2.x + m2.x * r9; v[9]  = c2.y + m2.y * r9;
    v[10] = c2.z + m2.z * r9; v[11] = c2.w + m2.w * r9;
    #pragma unroll
    for (int e = 0; e < 12; ++e) {
        v[e] += __shfl_xor(v[e], 16, 64);
        v[e] += __shfl_xor(v[e], 32, 64);
    }
    if ((t & 63) < 16) {
        #pragma unroll
        for (int j = 0; j < 3; ++j)
            #pragma unroll
            for (int e = 0; e < 4; ++e)
                ps[wv][j * 64 + l16 * 4 + e] = v[j * 4 + e];
    }
    __syncthreads();
    if (t < C_)
        gparte[(size_t)blockIdx.x * C_ + t] =
            (ps[0][t] + ps[1][t]) + (ps[2][t] + ps[3][t]);
}

// ---------------- pool partials: 196 blocks/image -> 4 segments ---------------
__global__ __launch_bounds__(192) void k_gred(const float* __restrict__ gparte,
        float* __restrict__ gpart) {
    int b = blockIdx.x >> 2, s = blockIdx.x & 3;   // grid 64
    int oc = threadIdx.x;
    float acc = 0.f;
    for (int sub = s * 49; sub < (s + 1) * 49; ++sub)
        acc += gparte[((size_t)(sub * 16 + b)) * C_ + oc];
    gpart[(size_t)(b * 4 + s) * C_ + oc] = acc;
}

// ---------------- MLP stage 1: z = gs@w1+b1 -> BN -> GELU -> zs ---------------
__global__ __launch_bounds__(256) void k_mlp1(const float* __restrict__ gpart,
        const float* __restrict__ w1, const float* __restrict__ b1,
        const float* __restrict__ gam, const float* __restrict__ bet,
        float* __restrict__ zs) {
    __shared__ float gs[B_ * C_];
    int t = threadIdx.x;
    int j = blockIdx.x * 256 + t;                  // 0..1023
    for (int f = t; f < B_ * C_; f += 256) {
        int b = f / C_, oc = f - b * C_;
        float a = 0.f;
        #pragma unroll
        for (int s = 0; s < 4; ++s) a += gpart[((size_t)(b * 4 + s)) * C_ + oc];
        gs[f] = a;
    }
    __syncthreads();
    float z[16];
    #pragma unroll
    for (int i = 0; i < 16; ++i) z[i] = b1[j];
    for (int c = 0; c < C_; ++c) {
        float w = w1[(size_t)c * PD_ + j];
        #pragma unroll
        for (int i = 0; i < 16; ++i) z[i] += gs[i * C_ + c] * w;
    }
    float mu = 0.f;
    #pragma unroll
    for (int i = 0; i < 16; ++i) mu += z[i];
    mu *= (1.0f / 16.0f);
    float var = 0.f;
    #pragma unroll
    for (int i = 0; i < 16; ++i) { float d = z[i] - mu; var += d * d; }
    var *= (1.0f / 16.0f);
    float sc = (1.0f / sqrtf(var + 1e-5f)) * gam[j];
    float bt = bet[j];
    #pragma unroll
    for (int i = 0; i < 16; ++i) {
        float zh = (z[i] - mu) * sc + bt;
        zs[(size_t)i * PD_ + j] = 0.5f * zh * (1.0f + erff(zh * 0.70710678118654752f));
    }
}

// ---------------- MLP stage 2: pred = zs @ w2 + b2 (w2 pre-transposed) --------
__global__ __launch_bounds__(64) void k_mlp2(const float* __restrict__ zs,
        const float* __restrict__ w2t, const float* __restrict__ b2,
        float* __restrict__ pred) {
    int i = blockIdx.x / NC_, jj = blockIdx.x - i * NC_;
    int lane = threadIdx.x;
    const float* zr = zs + (size_t)i * PD_;
    const float* wr = w2t + (size_t)jj * PD_;
    float a = 0.f;
    #pragma unroll
    for (int k = 0; k < 16; ++k) a += zr[lane + 64 * k] * wr[lane + 64 * k];
    a += __shfl_xor(a, 1, 64);  a += __shfl_xor(a, 2, 64);
    a += __shfl_xor(a, 4, 64);  a += __shfl_xor(a, 8, 64);
    a += __shfl_xor(a, 16, 64); a += __shfl_xor(a, 32, 64);
    if (lane == 0) pred[i * NC_ + jj] = a + b2[jj];
}

extern "C" void kernel_launch(void* const* d_in, const int* in_sizes, int n_in,
                              void* d_out, int out_size, void* d_ws, size_t ws_size,
                              hipStream_t stream) {
    const float* img    = (const float*)d_in[0];
    const float* conv_w = (const float*)d_in[1];
    const float* conv_b = (const float*)d_in[2];
    const float* gnn_w  = (const float*)d_in[3];
    const float* gnn_b  = (const float*)d_in[4];
    const float* w1     = (const float*)d_in[5];
    const float* b1     = (const float*)d_in[6];
    const float* bng    = (const float*)d_in[7];
    const float* bnb    = (const float*)d_in[8];
    const float* w2     = (const float*)d_in[9];
    const float* b2     = (const float*)d_in[10];
    float* out = (float*)d_out;

    float* XN            = (float*)d_ws;                        // BN*192 f32
    unsigned short* XS   = (unsigned short*)(XN + (size_t)BN_ * C_);  // BN*384
    unsigned int* TOPK   = (unsigned int*)(XS + (size_t)BN_ * 384);   // 7*BN*12
    int*   NBR12         = (int*)(TOPK + (size_t)NSEV * BN_ * 12);
    int*   NBR9          = NBR12 + (size_t)BN_ * 12;
    float* NORMS         = (float*)(NBR9 + (size_t)BN_ * K_);   // BN
    unsigned short* WSC  = (unsigned short*)(NORMS + BN_);      // 128*384
    unsigned short* WSG  = WSC + (size_t)128 * 384;             // 192*384
    float* GPART         = (float*)(WSG + (size_t)192 * 384);   // 64*C
    float* W2T           = GPART + (size_t)128 * C_;            // 100*1024
    float* Hh            = XN;            // reuse: XN dead after k_rescore
    float* GPARTE        = (float*)TOPK;  // reuse: TOPK dead after k_merge2
    float* ZS            = (float*)NBR12; // reuse: NBR12 dead after k_rescore

    k_normalize<<<784, 256, 0, stream>>>(img, XN, XS, NORMS);
    k_wsplit   <<<640, 256, 0, stream>>>(conv_w, gnn_w, w2, WSC, WSG, W2T);
    k_patchmfma<<<784, 256, 0, stream>>>(XS, WSC, NORMS, conv_b, out + OUT_PP);
    k_simmfma  <<<2800, 256, 0, stream>>>(XS, TOPK);
    k_merge2   <<<196, 256, 0, stream>>>(TOPK, NBR12);
    k_rescore  <<<3136, 256, 0, stream>>>(XN, NBR12, NBR9);
    k_gnnmfma  <<<392, 384, 0, stream>>>(XS, WSG, gnn_b, Hh);
    k_edge     <<<3136, 256, 0, stream>>>(Hh, NBR9, out + OUT_EATT, GPARTE);
    k_gred     <<<64, 192, 0, stream>>>(GPARTE, GPART);
    k_mlp1     <<<4, 256, 0, stream>>>(GPART, w1, b1, bng, bnb, ZS);
    k_mlp2     <<<1600, 64, 0, stream>>>(ZS, W2T, b2, out);
}

// Round 14
// 361.700 us; speedup vs baseline: 1.8182x; 1.3215x over previous
//
#include <hip/hip_runtime.h>
#include <math.h>

#define B_  16
#define C_  192
#define N_  3136
#define BN_ 50176
#define K_  9
#define NC_ 100
#define PD_ 1024
#define NSEV 7
#define SEVCOLS 448

#define OUT_EATT 1600
#define OUT_PP   453184

typedef short bf16x8 __attribute__((ext_vector_type(8)));
typedef float f32x16 __attribute__((ext_vector_type(16)));

__device__ __forceinline__ unsigned int umaxu(unsigned int a, unsigned int b) { return a > b ? a : b; }
__device__ __forceinline__ unsigned int med3u(unsigned int a, unsigned int b, unsigned int c) {
    unsigned int d;
    asm("v_med3_u32 %0, %1, %2, %3" : "=v"(d) : "v"(a), "v"(b), "v"(c));
    return d;
}
// insert key into sorted-desc lk[12]: L'[0]=max(L0,x), L'[k]=med3(L[k-1],L[k],x)
__device__ __forceinline__ void ins12m(unsigned int (&lk)[12], unsigned int key) {
    unsigned int nk[12];
    nk[0] = umaxu(lk[0], key);
    #pragma unroll
    for (int k = 1; k < 12; ++k) nk[k] = med3u(lk[k - 1], lk[k], key);
    #pragma unroll
    for (int k = 0; k < 12; ++k) lk[k] = nk[k];
}

// lexicographic (val desc, idx asc) insertion (rescore)
template<int NL>
__device__ inline void ins_lex(float (&lv)[NL], int (&li)[NL], float v, int vi) {
    if (v > lv[NL-1] || (v == lv[NL-1] && vi < li[NL-1])) {
        #pragma unroll
        for (int k = 0; k < NL; ++k) {
            bool p = (v > lv[k]) || (v == lv[k] && vi < li[k]);
            float fv = p ? lv[k] : v; int fi = p ? li[k] : vi;
            lv[k] = p ? v : lv[k];    li[k] = p ? vi : li[k];
            v = fv; vi = fi;
        }
    }
}

__device__ inline unsigned int bf16_rne(unsigned int u) {
    return (u + 0x7fffu + ((u >> 16) & 1u)) & 0xffff0000u;
}

// ---------------- normalize: [B,C,N] -> XN f32, XS bf16 hi|lo split, NORMS ----
__global__ __launch_bounds__(256) void k_normalize(const float* __restrict__ in,
        float* __restrict__ xn, unsigned short* __restrict__ xsn,
        float* __restrict__ norms) {
    __shared__ float tile[C_][65];
    __shared__ float part[4][64];
    __shared__ float rnorm_s[64];
    int b = blockIdx.x & 15;
    int n0 = (blockIdx.x >> 4) * 64;
    int t = threadIdx.x;
    for (int f = t; f < C_ * 64; f += 256) {
        int c = f >> 6, n = f & 63;
        tile[c][n] = in[((size_t)b * C_ + c) * N_ + n0 + n];
    }
    __syncthreads();
    {
        int n = t & 63, qq = t >> 6;
        float s = 0.f;
        #pragma unroll
        for (int i = 0; i < 48; ++i) { float v = tile[qq * 48 + i][n]; s += v * v; }
        part[qq][n] = s;
    }
    __syncthreads();
    if (t < 64) {
        float tot = part[0][t] + part[1][t] + part[2][t] + part[3][t];
        float nrm = fmaxf(sqrtf(tot), 1e-12f);
        norms[(size_t)b * N_ + n0 + t] = nrm;
        rnorm_s[t] = 1.0f / nrm;
    }
    __syncthreads();
    for (int f = t; f < 64 * 96; f += 256) {
        int n = f / 96, cp = f - n * 96;
        int c = cp * 2;
        float r = rnorm_s[n];
        float v0 = tile[c][n] * r;
        float v1 = tile[c + 1][n] * r;
        size_t row = (size_t)b * N_ + n0 + n;
        *(float2*)(xn + row * C_ + c) = make_float2(v0, v1);
        unsigned int h0 = bf16_rne(__float_as_uint(v0));
        unsigned int h1 = bf16_rne(__float_as_uint(v1));
        unsigned int l0 = bf16_rne(__float_as_uint(v0 - __uint_as_float(h0)));
        unsigned int l1 = bf16_rne(__float_as_uint(v1 - __uint_as_float(h1)));
        unsigned int* xr = (unsigned int*)(xsn + row * 384);
        xr[cp]      = (h0 >> 16) | (h1 & 0xffff0000u);
        xr[96 + cp] = (l0 >> 16) | (l1 & 0xffff0000u);
    }
}

// ---------------- split conv_w / gnn_w to bf16 hi|lo; transpose w2 ------------
__global__ __launch_bounds__(256) void k_wsplit(const float* __restrict__ cw,
        const float* __restrict__ gw, const float* __restrict__ w2,
        unsigned short* __restrict__ wsc, unsigned short* __restrict__ wsg,
        float* __restrict__ w2t) {
    int id = blockIdx.x * 256 + threadIdx.x;   // 640*256 = 163840
    if (id < 128 * 192) {
        int k = id / 192, c = id - k * 192;
        float v = (k < 100) ? cw[k * 192 + c] : 0.f;
        unsigned int h = bf16_rne(__float_as_uint(v));
        wsc[(size_t)k * 384 + c] = (unsigned short)(h >> 16);
        wsc[(size_t)k * 384 + 192 + c] =
            (unsigned short)(bf16_rne(__float_as_uint(v - __uint_as_float(h))) >> 16);
    } else if (id < 61440) {
        int e = id - 128 * 192;
        int cc = e / 192, j = e - cc * 192;
        float v = gw[cc * 192 + j];
        unsigned int h = bf16_rne(__float_as_uint(v));
        wsg[(size_t)j * 384 + cc] = (unsigned short)(h >> 16);
        wsg[(size_t)j * 384 + 192 + cc] =
            (unsigned short)(bf16_rne(__float_as_uint(v - __uint_as_float(h))) >> 16);
    } else {
        int e2 = id - 61440;                   // 0..102399
        int jj = e2 >> 10, k = e2 & 1023;
        w2t[(size_t)jj * PD_ + k] = w2[(size_t)k * NC_ + jj];
    }
}

// stage one 32-col chunk via global_load_lds; NLW = glds per wave
#define STAGE32(DST, SRCBASE, NLW) { \
    const char* s_ = (SRCBASE); \
    _Pragma("unroll") \
    for (int q_ = 0; q_ < NLW; ++q_) \
        __builtin_amdgcn_global_load_lds( \
            (const __attribute__((address_space(1))) unsigned int*)(s_ + q_ * 32), \
            (__attribute__((address_space(3))) unsigned int*)((DST) + (w * NLW + q_) * 1024), 16, 0, 0); }

// stage one K-HALF of a 32-col chunk (12KB); NLW glds per wave (NLW*waves=12)
#define STAGEHALF(DST, BASE, COLB, KH, NLW) { \
    _Pragma("unroll") \
    for (int q_ = 0; q_ < NLW; ++q_) { \
        const char* s_ = (BASE) + (size_t)((COLB) + l31) * 768 + (KH) * 384 + (w * (NLW) + q_) * 32 + lh * 16; \
        __builtin_amdgcn_global_load_lds( \
            (const __attribute__((address_space(1))) unsigned int*)s_, \
            (__attribute__((address_space(3))) unsigned int*)((DST) + (w * (NLW) + q_) * 1024), 16, 0, 0); } }

// 16-candidate packed-key scan into lk[12] (med3); off-diagonal chunk (no self test)
#define SCAN16 { \
    int c0 = cbase + c * 32 + 4 * lh; \
    int kc = 4095 - c0; \
    _Pragma("unroll") \
    for (int g = 0; g < 4; ++g) { \
        _Pragma("unroll") \
        for (int q = 0; q < 4; ++q) { \
            unsigned int u = __float_as_uint(fmaf(acc[4 * g + q], 0.125f, 0.75f)); \
            unsigned int key = ((u >> 3) << 12) | (unsigned int)(kc - (8 * g + q)); \
            ins12m(lk, key); \
        } \
    } }
// diagonal-chunk variant: zero the self column
#define SCAN16D { \
    int c0 = cbase + c * 32 + 4 * lh; \
    int selfslot = r - c0; \
    int kc = 4095 - c0; \
    _Pragma("unroll") \
    for (int g = 0; g < 4; ++g) { \
        _Pragma("unroll") \
        for (int q = 0; q < 4; ++q) { \
            unsigned int u = __float_as_uint(fmaf(acc[4 * g + q], 0.125f, 0.75f)); \
            unsigned int key = ((u >> 3) << 12) | (unsigned int)(kc - (8 * g + q)); \
            key = (8 * g + q == selfslot) ? 0u : key; \
            ins12m(lk, key); \
        } \
    } }

// ---------------- MFMA sim + branchless packed-u32 top-12 ----------
// grid 2800: img(16) x rowblk(25) x seventh(7). 4 waves x 32 rows = 128 rows.
// K-split double buffer (2x12KB). REGISTER GEOMETRY IS LOAD-BEARING:
// (256,3) -> 80 VGPR, no spill, 188us. (256,4) -> 64 VGPR + scratch spill,
// 308us. (256,5) -> 48 VGPR, heavy spill, 485us. bfrag[24]=96 regs + acc
// needs the 3-waves/EU budget. DO NOT RAISE THE BOUND.
// Packed key: fmaf(v,0.125,0.75) in [0.625,0.875] -> one exponent for |v|<2
// -> uint-monotone mantissa; key = mant[22:3]<<12 | (4095-col).
// Partner merge snapshots before insert (round-7 lesson).
__global__ __launch_bounds__(256, 3) void k_simmfma(const unsigned short* __restrict__ xs,
        unsigned int* __restrict__ topk) {
    __shared__ __align__(1024) char SMEM[24576];
    int bid = blockIdx.x;
    int img = bid & 15;
    int rest = bid >> 4;            // 0..174
    int rb = rest / NSEV;           // 0..24
    int sv = rest - rb * NSEV;      // 0..6
    int t = threadIdx.x;
    int w = t >> 6, lane = t & 63;
    int l31 = lane & 31, lh = lane >> 5;
    const char* xsi = (const char*)(xs + (size_t)img * N_ * 384);

    int r = rb * 128 + w * 32 + l31;
    bool valid = r < N_;
    int rl = valid ? r : (N_ - 1);
    bf16x8 bfrag[24];
    {
        const char* rp = xsi + (size_t)rl * 768 + lh * 16;
        #pragma unroll
        for (int ks = 0; ks < 24; ++ks)
            bfrag[ks] = *(const bf16x8*)(rp + ks * 32);
    }
    unsigned int lk[12];
    #pragma unroll
    for (int k = 0; k < 12; ++k) lk[k] = 0u;

    int cbase = sv * SEVCOLS;
    int c_self = rb * 4 + w - sv * 14;   // wave-uniform diag chunk (may be out of [0,14))

    STAGEHALF(SMEM, xsi, cbase, 0, 3)
    __syncthreads();

    for (int c = 0; c < 14; ++c) {
        STAGEHALF(SMEM + 12288, xsi, cbase + c * 32, 1, 3)
        f32x16 acc;
        #pragma unroll
        for (int i = 0; i < 16; ++i) acc[i] = 0.f;
        {
            const char* rp = SMEM + lh * 512 + l31 * 16;
            __builtin_amdgcn_s_setprio(1);
            #pragma unroll
            for (int ks = 0; ks < 12; ++ks) {
                bf16x8 af = *(const bf16x8*)(rp + ks * 1024);
                acc = __builtin_amdgcn_mfma_f32_32x32x16_bf16(af, bfrag[ks], acc, 0, 0, 0);
            }
            __builtin_amdgcn_s_setprio(0);
        }
        __syncthreads();
        if (c < 13) { STAGEHALF(SMEM, xsi, cbase + (c + 1) * 32, 0, 3) }
        {
            const char* rp = SMEM + 12288 + lh * 512 + l31 * 16;
            __builtin_amdgcn_s_setprio(1);
            #pragma unroll
            for (int ks = 0; ks < 12; ++ks) {
                bf16x8 af = *(const bf16x8*)(rp + ks * 1024);
                acc = __builtin_amdgcn_mfma_f32_32x32x16_bf16(af, bfrag[12 + ks], acc, 0, 0, 0);
            }
            __builtin_amdgcn_s_setprio(0);
        }
        if (valid) {
            if (c == c_self) SCAN16D
            else             SCAN16
        }
        __syncthreads();
    }
    // merge partner lane: snapshot ALL partner keys first, then insert
    unsigned int pk[12];
    #pragma unroll
    for (int j = 0; j < 12; ++j)
        pk[j] = (unsigned int)__shfl_xor((int)lk[j], 32, 64);
    #pragma unroll
    for (int j = 0; j < 12; ++j) ins12m(lk, pk[j]);
    if (valid && lh == 0) {
        unsigned int* op = topk + ((size_t)sv * BN_ + (size_t)img * N_ + r) * 12;
        #pragma unroll
        for (int k = 0; k < 12; ++k) op[k] = lk[k];
    }
}

// ---------------- patch head via MFMA (K-split 24KB, occupancy 3) -------------
// Same bfrag[24] structure as simmfma: same spill cliff. Keep (256,3).
__global__ __launch_bounds__(256, 3) void k_patchmfma(const unsigned short* __restrict__ xs,
        const unsigned short* __restrict__ wsc, const float* __restrict__ norms,
        const float* __restrict__ cb, float* __restrict__ outp) {
    __shared__ __align__(1024) char SMEM[24576];
    int bid = blockIdx.x;
    int img = bid & 15;
    int n0 = (bid >> 4) * 64;
    int t = threadIdx.x;
    int w = t >> 6, lane = t & 63;
    int l31 = lane & 31, lh = lane >> 5;
    const char* xsi = (const char*)(xs + (size_t)img * N_ * 384);
    int ch = w * 32 + l31;
    bf16x8 bfrag[24];
    {
        const char* wp = (const char*)wsc + (size_t)ch * 768 + lh * 16;
        #pragma unroll
        for (int ks = 0; ks < 24; ++ks)
            bfrag[ks] = *(const bf16x8*)(wp + ks * 32);
    }
    float bias = (ch < NC_) ? cb[ch] : 0.f;
    STAGEHALF(SMEM, xsi, n0, 0, 3)
    __syncthreads();
    for (int c = 0; c < 2; ++c) {
        STAGEHALF(SMEM + 12288, xsi, n0 + c * 32, 1, 3)
        f32x16 acc;
        #pragma unroll
        for (int i = 0; i < 16; ++i) acc[i] = 0.f;
        {
            const char* rp = SMEM + lh * 512 + l31 * 16;
            #pragma unroll
            for (int ks = 0; ks < 12; ++ks) {
                bf16x8 af = *(const bf16x8*)(rp + ks * 1024);
                acc = __builtin_amdgcn_mfma_f32_32x32x16_bf16(af, bfrag[ks], acc, 0, 0, 0);
            }
        }
        __syncthreads();
        if (c == 0) { STAGEHALF(SMEM, xsi, n0 + 32, 0, 3) }
        {
            const char* rp = SMEM + 12288 + lh * 512 + l31 * 16;
            #pragma unroll
            for (int ks = 0; ks < 12; ++ks) {
                bf16x8 af = *(const bf16x8*)(rp + ks * 1024);
                acc = __builtin_amdgcn_mfma_f32_32x32x16_bf16(af, bfrag[12 + ks], acc, 0, 0, 0);
            }
        }
        if (ch < NC_) {
            int nb = n0 + c * 32 + 4 * lh;
            float* op = outp + ((size_t)(img * NC_ + ch)) * N_ + nb;
            const float* npv = norms + (size_t)img * N_ + nb;
            #pragma unroll
            for (int g = 0; g < 4; ++g) {
                float4 nv = *(const float4*)(npv + 8 * g);
                float4 o;
                o.x = acc[4 * g + 0] * nv.x + bias;
                o.y = acc[4 * g + 1] * nv.y + bias;
                o.z = acc[4 * g + 2] * nv.z + bias;
                o.w = acc[4 * g + 3] * nv.w + bias;
                *(float4*)(op + 8 * g) = o;
            }
        }
        __syncthreads();
    }
}

// ---------------- GNN linear+relu via MFMA: h = relu(XS @ WSG^T + b) ---------
__global__ __launch_bounds__(384, 3) void k_gnnmfma(const unsigned short* __restrict__ xs,
        const unsigned short* __restrict__ wsg, const float* __restrict__ gbias,
        float* __restrict__ h) {
    __shared__ __align__(1024) char SMEM[49152];
    int n0 = blockIdx.x * 128;
    int t = threadIdx.x;
    int w = t / 64, lane = t & 63;
    int l31 = lane & 31, lh = lane >> 5;
    int j = w * 32 + l31;
    bf16x8 bfrag[24];
    {
        const char* wp = (const char*)wsg + (size_t)j * 768 + lh * 16;
        #pragma unroll
        for (int ks = 0; ks < 24; ++ks)
            bfrag[ks] = *(const bf16x8*)(wp + ks * 32);
    }
    float bj = gbias[j];
    STAGE32(SMEM, (const char*)xs + (size_t)(n0 + l31) * 768 + w * 128 + lh * 16, 4);
    __syncthreads();
    for (int c = 0; c < 4; ++c) {
        char* cur = SMEM + (c & 1) * 24576;
        if (c < 3) {
            char* dst = SMEM + ((c & 1) ^ 1) * 24576;
            STAGE32(dst, (const char*)xs + (size_t)(n0 + (c + 1) * 32 + l31) * 768 + w * 128 + lh * 16, 4);
        }
        f32x16 acc;
        #pragma unroll
        for (int i = 0; i < 16; ++i) acc[i] = 0.f;
        const char* rp = cur + lh * 512 + l31 * 16;
        #pragma unroll
        for (int ks = 0; ks < 24; ++ks) {
            bf16x8 af = *(const bf16x8*)(rp + ks * 1024);
            acc = __builtin_amdgcn_mfma_f32_32x32x16_bf16(af, bfrag[ks], acc, 0, 0, 0);
        }
        int nb = n0 + c * 32 + 4 * lh;
        #pragma unroll
        for (int g = 0; g < 4; ++g)
            #pragma unroll
            for (int q = 0; q < 4; ++q)
                h[(size_t)(nb + 8 * g + q) * C_ + j] = fmaxf(acc[4 * g + q] + bj, 0.f);
        __syncthreads();
    }
}

// ---------------- merge 7 per-seventh packed lists -> top-12 candidates -------
__global__ __launch_bounds__(256) void k_merge2(const unsigned int* __restrict__ topk,
        int* __restrict__ nbr12) {
    int row = blockIdx.x * 256 + threadIdx.x;      // 50176
    unsigned int lk[12];
    const unsigned int* p0 = topk + (size_t)row * 12;
    #pragma unroll
    for (int k = 0; k < 12; ++k) lk[k] = p0[k];
    #pragma unroll
    for (int h = 1; h < NSEV; ++h) {
        const unsigned int* p1 = topk + ((size_t)h * BN_ + row) * 12;
        #pragma unroll
        for (int j = 0; j < 12; ++j) ins12m(lk, p1[j]);
    }
    int gb = (row / N_) * N_;
    int* np = nbr12 + (size_t)row * 12;
    #pragma unroll
    for (int k = 0; k < 12; ++k) np[k] = gb + (4095 - (int)(lk[k] & 0xFFFu));
}

// -------- exact fp32 rescore, cooperative 16-lane (coalesced gathers) ---------
// 16 rows/block; per row: 16 lanes hold 12 channels each (3 float4).
__global__ __launch_bounds__(256) void k_rescore(const float* __restrict__ xn,
        const int* __restrict__ nbr12, int* __restrict__ nbr9) {
    int img = blockIdx.x & 15;
    int sub = blockIdx.x >> 4;                     // 0..195
    int t = threadIdx.x;
    int nl = t >> 4, l16 = t & 15;
    int row = img * N_ + sub * 16 + nl;
    const float4* xa = (const float4*)(xn + (size_t)row * C_) + l16;
    float4 a0 = xa[0], a1 = xa[16], a2 = xa[32];
    const int* np12 = nbr12 + (size_t)row * 12;
    float d[12]; int ci[12];
    #pragma unroll
    for (int j = 0; j < 12; ++j) {
        int cand = np12[j];                        // wave-uniform per 16-group
        ci[j] = cand;
        const float4* xb = (const float4*)(xn + (size_t)cand * C_) + l16;
        float4 b0 = xb[0], b1 = xb[16], b2 = xb[32];
        float s = a0.x*b0.x + a0.y*b0.y + a0.z*b0.z + a0.w*b0.w
                + a1.x*b1.x + a1.y*b1.y + a1.z*b1.z + a1.w*b1.w
                + a2.x*b2.x + a2.y*b2.y + a2.z*b2.z + a2.w*b2.w;
        s += __shfl_xor(s, 1, 64);
        s += __shfl_xor(s, 2, 64);
        s += __shfl_xor(s, 4, 64);
        s += __shfl_xor(s, 8, 64);
        d[j] = (cand != row) ? s : -1e30f;
    }
    float lv[9]; int li[9];
    #pragma unroll
    for (int k = 0; k < 9; ++k) { lv[k] = -1e30f; li[k] = 0x7fffffff; }
    #pragma unroll
    for (int j = 0; j < 12; ++j) ins_lex<9>(lv, li, d[j], ci[j]);
    if (l16 == 0) {
        int* np = nbr9 + (size_t)row * 9;
        #pragma unroll
        for (int k = 0; k < 9; ++k) np[k] = li[k];
    }
}

// -------- edge attention + aggregation + pool partial (16 lanes/node) ---------
__global__ __launch_bounds__(256) void k_edge(const float* __restrict__ h,
        const int* __restrict__ nbr, float* __restrict__ eatt,
        float* __restrict__ gparte) {
    __shared__ float ps[4][C_];
    int img = blockIdx.x & 15;
    int sub = blockIdx.x >> 4;                     // 0..195
    int t = threadIdx.x;
    int wv = t >> 6;
    int nl = t >> 4;                               // node-local 0..15
    int l16 = t & 15;
    int node = img * N_ + sub * 16 + nl;
    const float4* hc = (const float4*)(h + (size_t)node * C_) + l16;
    float4 c0 = hc[0], c1 = hc[16], c2 = hc[32];
    float4 m0 = make_float4(0,0,0,0), m1 = make_float4(0,0,0,0), m2 = make_float4(0,0,0,0);
    const int* np_ = nbr + (size_t)node * K_;
    float* ep = eatt + (size_t)node * K_;
    #pragma unroll
    for (int k = 0; k < K_; ++k) {
        int src = np_[k];
        const float4* hs = (const float4*)(h + (size_t)src * C_) + l16;
        float4 s0 = hs[0], s1 = hs[16], s2 = hs[32];
        float d = s0.x*c0.x + s0.y*c0.y + s0.z*c0.z + s0.w*c0.w
                + s1.x*c1.x + s1.y*c1.y + s1.z*c1.z + s1.w*c1.w
                + s2.x*c2.x + s2.y*c2.y + s2.z*c2.z + s2.w*c2.w;
        d += __shfl_xor(d, 1, 64);
        d += __shfl_xor(d, 2, 64);
        d += __shfl_xor(d, 4, 64);
        d += __shfl_xor(d, 8, 64);
        if (l16 == 0) ep[k] = 1.0f / (1.0f + expf(-d));
        m0.x += s0.x; m0.y += s0.y; m0.z += s0.z; m0.w += s0.w;
        m1.x += s1.x; m1.y += s1.y; m1.z += s1.z; m1.w += s1.w;
        m2.x += s2.x; m2.y += s2.y; m2.z += s2.z; m2.w += s2.w;
    }
    const float r9 = 1.0f / 9.0f;
    float v[12];
    v[0] = c0.x + m0.x * r9; v[1]  = c0.y + m0.y * r9;
    v[2] = c0.z + m0.z * r9; v[3]  = c0.w + m0.w * r9;
    v[4] = c1.x + m1.x * r9; v[5]  = c1.y + m1.y * r9;
    v[6] = c1.z + m1.z * r9; v[7]  = c1.w + m1.w * r9;
    v[8] = c2.x + m2.x * r9; v[9]  = c2.y + m2.y * r9;
    v[10] = c2.z + m2.z * r9; v[11] = c2.w + m2.w * r9;
    #pragma unroll
    for (int e = 0; e < 12; ++e) {
        v[e] += __shfl_xor(v[e], 16, 64);
        v[e] += __shfl_xor(v[e], 32, 64);
    }
    if ((t & 63) < 16) {
        #pragma unroll
        for (int j = 0; j < 3; ++j)
            #pragma unroll
            for (int e = 0; e < 4; ++e)
                ps[wv][j * 64 + l16 * 4 + e] = v[j * 4 + e];
    }
    __syncthreads();
    if (t < C_)
        gparte[(size_t)blockIdx.x * C_ + t] =
            (ps[0][t] + ps[1][t]) + (ps[2][t] + ps[3][t]);
}

// ---------------- pool partials: 196 blocks/image -> 4 segments ---------------
__global__ __launch_bounds__(192) void k_gred(const float* __restrict__ gparte,
        float* __restrict__ gpart) {
    int b = blockIdx.x >> 2, s = blockIdx.x & 3;   // grid 64
    int oc = threadIdx.x;
    float acc = 0.f;
    for (int sub = s * 49; sub < (s + 1) * 49; ++sub)
        acc += gparte[((size_t)(sub * 16 + b)) * C_ + oc];
    gpart[(size_t)(b * 4 + s) * C_ + oc] = acc;
}

// ---------------- MLP stage 1: z = gs@w1+b1 -> BN -> GELU -> zs ---------------
__global__ __launch_bounds__(256) void k_mlp1(const float* __restrict__ gpart,
        const float* __restrict__ w1, const float* __restrict__ b1,
        const float* __restrict__ gam, const float* __restrict__ bet,
        float* __restrict__ zs) {
    __shared__ float gs[B_ * C_];
    int t = threadIdx.x;
    int j = blockIdx.x * 256 + t;                  // 0..1023
    for (int f = t; f < B_ * C_; f += 256) {
        int b = f / C_, oc = f - b * C_;
        float a = 0.f;
        #pragma unroll
        for (int s = 0; s < 4; ++s) a += gpart[((size_t)(b * 4 + s)) * C_ + oc];
        gs[f] = a;
    }
    __syncthreads();
    float z[16];
    #pragma unroll
    for (int i = 0; i < 16; ++i) z[i] = b1[j];
    for (int c = 0; c < C_; ++c) {
        float w = w1[(size_t)c * PD_ + j];
        #pragma unroll
        for (int i = 0; i < 16; ++i) z[i] += gs[i * C_ + c] * w;
    }
    float mu = 0.f;
    #pragma unroll
    for (int i = 0; i < 16; ++i) mu += z[i];
    mu *= (1.0f / 16.0f);
    float var = 0.f;
    #pragma unroll
    for (int i = 0; i < 16; ++i) { float d = z[i] - mu; var += d * d; }
    var *= (1.0f / 16.0f);
    float sc = (1.0f / sqrtf(var + 1e-5f)) * gam[j];
    float bt = bet[j];
    #pragma unroll
    for (int i = 0; i < 16; ++i) {
        float zh = (z[i] - mu) * sc + bt;
        zs[(size_t)i * PD_ + j] = 0.5f * zh * (1.0f + erff(zh * 0.70710678118654752f));
    }
}

// ---------------- MLP stage 2: pred = zs @ w2 + b2 (w2 pre-transposed) --------
__global__ __launch_bounds__(64) void k_mlp2(const float* __restrict__ zs,
        const float* __restrict__ w2t, const float* __restrict__ b2,
        float* __restrict__ pred) {
    int i = blockIdx.x / NC_, jj = blockIdx.x - i * NC_;
    int lane = threadIdx.x;
    const float* zr = zs + (size_t)i * PD_;
    const float* wr = w2t + (size_t)jj * PD_;
    float a = 0.f;
    #pragma unroll
    for (int k = 0; k < 16; ++k) a += zr[lane + 64 * k] * wr[lane + 64 * k];
    a += __shfl_xor(a, 1, 64);  a += __shfl_xor(a, 2, 64);
    a += __shfl_xor(a, 4, 64);  a += __shfl_xor(a, 8, 64);
    a += __shfl_xor(a, 16, 64); a += __shfl_xor(a, 32, 64);
    if (lane == 0) pred[i * NC_ + jj] = a + b2[jj];
}

extern "C" void kernel_launch(void* const* d_in, const int* in_sizes, int n_in,
                              void* d_out, int out_size, void* d_ws, size_t ws_size,
                              hipStream_t stream) {
    const float* img    = (const float*)d_in[0];
    const float* conv_w = (const float*)d_in[1];
    const float* conv_b = (const float*)d_in[2];
    const float* gnn_w  = (const float*)d_in[3];
    const float* gnn_b  = (const float*)d_in[4];
    const float* w1     = (const float*)d_in[5];
    const float* b1     = (const float*)d_in[6];
    const float* bng    = (const float*)d_in[7];
    const float* bnb    = (const float*)d_in[8];
    const float* w2     = (const float*)d_in[9];
    const float* b2     = (const float*)d_in[10];
    float* out = (float*)d_out;

    float* XN            = (float*)d_ws;                        // BN*192 f32
    unsigned short* XS   = (unsigned short*)(XN + (size_t)BN_ * C_);  // BN*384
    unsigned int* TOPK   = (unsigned int*)(XS + (size_t)BN_ * 384);   // 7*BN*12
    int*   NBR12         = (int*)(TOPK + (size_t)NSEV * BN_ * 12);
    int*   NBR9          = NBR12 + (size_t)BN_ * 12;
    float* NORMS         = (float*)(NBR9 + (size_t)BN_ * K_);   // BN
    unsigned short* WSC  = (unsigned short*)(NORMS + BN_);      // 128*384
    unsigned short* WSG  = WSC + (size_t)128 * 384;             // 192*384
    float* GPART         = (float*)(WSG + (size_t)192 * 384);   // 64*C
    float* W2T           = GPART + (size_t)128 * C_;            // 100*1024
    float* Hh            = XN;            // reuse: XN dead after k_rescore
    float* GPARTE        = (float*)TOPK;  // reuse: TOPK dead after k_merge2
    float* ZS            = (float*)NBR12; // reuse: NBR12 dead after k_rescore

    k_normalize<<<784, 256, 0, stream>>>(img, XN, XS, NORMS);
    k_wsplit   <<<640, 256, 0, stream>>>(conv_w, gnn_w, w2, WSC, WSG, W2T);
    k_patchmfma<<<784, 256, 0, stream>>>(XS, WSC, NORMS, conv_b, out + OUT_PP);
    k_simmfma  <<<2800, 256, 0, stream>>>(XS, TOPK);
    k_merge2   <<<196, 256, 0, stream>>>(TOPK, NBR12);
    k_rescore  <<<3136, 256, 0, stream>>>(XN, NBR12, NBR9);
    k_gnnmfma  <<<392, 384, 0, stream>>>(XS, WSG, gnn_b, Hh);
    k_edge     <<<3136, 256, 0, stream>>>(Hh, NBR9, out + OUT_EATT, GPARTE);
    k_gred     <<<64, 192, 0, stream>>>(GPARTE, GPART);
    k_mlp1     <<<4, 256, 0, stream>>>(GPART, w1, b1, bng, bnb, ZS);
    k_mlp2     <<<1600, 64, 0, stream>>>(ZS, W2T, b2, out);
}

// Round 15
// 347.484 us; speedup vs baseline: 1.8926x; 1.0409x over previous
//
#include <hip/hip_runtime.h>
#include <math.h>

#define B_  16
#define C_  192
#define N_  3136
#define BN_ 50176
#define K_  9
#define NC_ 100
#define PD_ 1024
#define NSEV 7
#define SEVCOLS 448
#define TILEB 24576          // bytes per 32-col tile pair (hi+lo)
#define HALFB 12288

#define OUT_EATT 1600
#define OUT_PP   453184

typedef short bf16x8 __attribute__((ext_vector_type(8)));
typedef float f32x16 __attribute__((ext_vector_type(16)));

__device__ __forceinline__ unsigned int umaxu(unsigned int a, unsigned int b) { return a > b ? a : b; }
__device__ __forceinline__ unsigned int med3u(unsigned int a, unsigned int b, unsigned int c) {
    unsigned int d;
    asm("v_med3_u32 %0, %1, %2, %3" : "=v"(d) : "v"(a), "v"(b), "v"(c));
    return d;
}
// insert key into sorted-desc lk[12]: L'[0]=max(L0,x), L'[k]=med3(L[k-1],L[k],x)
__device__ __forceinline__ void ins12m(unsigned int (&lk)[12], unsigned int key) {
    unsigned int nk[12];
    nk[0] = umaxu(lk[0], key);
    #pragma unroll
    for (int k = 1; k < 12; ++k) nk[k] = med3u(lk[k - 1], lk[k], key);
    #pragma unroll
    for (int k = 0; k < 12; ++k) lk[k] = nk[k];
}

// lexicographic (val desc, idx asc) insertion (rescore)
template<int NL>
__device__ inline void ins_lex(float (&lv)[NL], int (&li)[NL], float v, int vi) {
    if (v > lv[NL-1] || (v == lv[NL-1] && vi < li[NL-1])) {
        #pragma unroll
        for (int k = 0; k < NL; ++k) {
            bool p = (v > lv[k]) || (v == lv[k] && vi < li[k]);
            float fv = p ? lv[k] : v; int fi = p ? li[k] : vi;
            lv[k] = p ? v : lv[k];    li[k] = p ? vi : li[k];
            v = fv; vi = fi;
        }
    }
}

__device__ inline unsigned int bf16_rne(unsigned int u) {
    return (u + 0x7fffu + ((u >> 16) & 1u)) & 0xffff0000u;
}

// XS2 tiled layout: per 32-col block cb (global, 32|N and 32|BN), per K-half kh:
// 12KB tile at cb*24576 + kh*12288; within: addr = ks*1024 + lh*512 + l31*16 + off
// where col = cb*32 + l31, byte-in-half bo = ks*32 + lh*16 + off.
// This is EXACTLY the MFMA fragment consumption order -> all global_load_lds
// and bfrag reads become contiguous 1KB per wave-instruction (coalesced).

// ---------------- normalize: [B,C,N] -> XN f32, XS2 tiled bf16 hi|lo, NORMS --
__global__ __launch_bounds__(256) void k_normalize(const float* __restrict__ in,
        float* __restrict__ xn, char* __restrict__ xs2,
        float* __restrict__ norms) {
    __shared__ float tile[C_][65];
    __shared__ float part[4][64];
    __shared__ float rnorm_s[64];
    int b = blockIdx.x & 15;
    int n0 = (blockIdx.x >> 4) * 64;
    int t = threadIdx.x;
    for (int f = t; f < C_ * 64; f += 256) {
        int c = f >> 6, n = f & 63;
        tile[c][n] = in[((size_t)b * C_ + c) * N_ + n0 + n];
    }
    __syncthreads();
    {
        int n = t & 63, qq = t >> 6;
        float s = 0.f;
        #pragma unroll
        for (int i = 0; i < 48; ++i) { float v = tile[qq * 48 + i][n]; s += v * v; }
        part[qq][n] = s;
    }
    __syncthreads();
    if (t < 64) {
        float tot = part[0][t] + part[1][t] + part[2][t] + part[3][t];
        float nrm = fmaxf(sqrtf(tot), 1e-12f);
        norms[(size_t)b * N_ + n0 + t] = nrm;
        rnorm_s[t] = 1.0f / nrm;
    }
    __syncthreads();
    for (int f = t; f < 64 * 96; f += 256) {
        int n = f / 96, cp = f - n * 96;
        int c = cp * 2;
        float r = rnorm_s[n];
        float v0 = tile[c][n] * r;
        float v1 = tile[c + 1][n] * r;
        int row = b * N_ + n0 + n;
        *(float2*)(xn + (size_t)row * C_ + c) = make_float2(v0, v1);
        unsigned int h0 = bf16_rne(__float_as_uint(v0));
        unsigned int h1 = bf16_rne(__float_as_uint(v1));
        unsigned int l0 = bf16_rne(__float_as_uint(v0 - __uint_as_float(h0)));
        unsigned int l1 = bf16_rne(__float_as_uint(v1 - __uint_as_float(h1)));
        int cb = row >> 5, l31 = row & 31;
        int ks = cp >> 3, lh = (cp >> 2) & 1, off = 4 * (cp & 3);
        char* base = xs2 + (size_t)cb * TILEB + ks * 1024 + lh * 512 + l31 * 16 + off;
        *(unsigned int*)base           = (h0 >> 16) | (h1 & 0xffff0000u);
        *(unsigned int*)(base + HALFB) = (l0 >> 16) | (l1 & 0xffff0000u);
    }
}

// ---------------- split conv_w / gnn_w to bf16 hi|lo; transpose w2 ------------
__global__ __launch_bounds__(256) void k_wsplit(const float* __restrict__ cw,
        const float* __restrict__ gw, const float* __restrict__ w2,
        unsigned short* __restrict__ wsc, unsigned short* __restrict__ wsg,
        float* __restrict__ w2t) {
    int id = blockIdx.x * 256 + threadIdx.x;   // 640*256 = 163840
    if (id < 128 * 192) {
        int k = id / 192, c = id - k * 192;
        float v = (k < 100) ? cw[k * 192 + c] : 0.f;
        unsigned int h = bf16_rne(__float_as_uint(v));
        wsc[(size_t)k * 384 + c] = (unsigned short)(h >> 16);
        wsc[(size_t)k * 384 + 192 + c] =
            (unsigned short)(bf16_rne(__float_as_uint(v - __uint_as_float(h))) >> 16);
    } else if (id < 61440) {
        int e = id - 128 * 192;
        int cc = e / 192, j = e - cc * 192;
        float v = gw[cc * 192 + j];
        unsigned int h = bf16_rne(__float_as_uint(v));
        wsg[(size_t)j * 384 + cc] = (unsigned short)(h >> 16);
        wsg[(size_t)j * 384 + 192 + cc] =
            (unsigned short)(bf16_rne(__float_as_uint(v - __uint_as_float(h))) >> 16);
    } else {
        int e2 = id - 61440;                   // 0..102399
        int jj = e2 >> 10, k = e2 & 1023;
        w2t[(size_t)jj * PD_ + k] = w2[(size_t)k * NC_ + jj];
    }
}

// stage one 12KB tile-half (contiguous, coalesced); NLW glds/wave, NLW*waves=12
#define STAGETILE(DST, BASE, CB, KH, NLW) { \
    _Pragma("unroll") \
    for (int q_ = 0; q_ < NLW; ++q_) { \
        const char* s_ = (BASE) + (size_t)(CB) * TILEB + (KH) * HALFB + (w * (NLW) + q_) * 1024 + lane * 16; \
        __builtin_amdgcn_global_load_lds( \
            (const __attribute__((address_space(1))) unsigned int*)s_, \
            (__attribute__((address_space(3))) unsigned int*)((DST) + (w * (NLW) + q_) * 1024), 16, 0, 0); } }
// stage a full 24KB tile pair (gnn: 6 waves x 4 segs)
#define STAGEPAIR(DST, BASE, CB, NLW) { \
    _Pragma("unroll") \
    for (int q_ = 0; q_ < NLW; ++q_) { \
        const char* s_ = (BASE) + (size_t)(CB) * TILEB + (w * (NLW) + q_) * 1024 + lane * 16; \
        __builtin_amdgcn_global_load_lds( \
            (const __attribute__((address_space(1))) unsigned int*)s_, \
            (__attribute__((address_space(3))) unsigned int*)((DST) + (w * (NLW) + q_) * 1024), 16, 0, 0); } }

// 16-candidate packed-key scan into lk[12] (med3); off-diagonal chunk (no self test)
#define SCAN16 { \
    int c0 = cbase + c * 32 + 4 * lh; \
    int kc = 4095 - c0; \
    _Pragma("unroll") \
    for (int g = 0; g < 4; ++g) { \
        _Pragma("unroll") \
        for (int q = 0; q < 4; ++q) { \
            unsigned int u = __float_as_uint(fmaf(acc[4 * g + q], 0.125f, 0.75f)); \
            unsigned int key = ((u >> 3) << 12) | (unsigned int)(kc - (8 * g + q)); \
            ins12m(lk, key); \
        } \
    } }
// diagonal-chunk variant: zero the self column
#define SCAN16D { \
    int c0 = cbase + c * 32 + 4 * lh; \
    int selfslot = r - c0; \
    int kc = 4095 - c0; \
    _Pragma("unroll") \
    for (int g = 0; g < 4; ++g) { \
        _Pragma("unroll") \
        for (int q = 0; q < 4; ++q) { \
            unsigned int u = __float_as_uint(fmaf(acc[4 * g + q], 0.125f, 0.75f)); \
            unsigned int key = ((u >> 3) << 12) | (unsigned int)(kc - (8 * g + q)); \
            key = (8 * g + q == selfslot) ? 0u : key; \
            ins12m(lk, key); \
        } \
    } }

// ---------------- MFMA sim + branchless packed-u32 top-12 ----------
// grid 2800: img(16) x rowblk(25) x seventh(7). 4 waves x 32 rows = 128 rows.
// K-split double buffer (2x12KB), tiled XS2 (all loads coalesced).
// REGISTER GEOMETRY IS LOAD-BEARING: (256,3) -> no spill, 186us;
// (256,4)/(256,5) -> scratch spill, 308/485us. DO NOT RAISE THE BOUND.
// Packed key: fmaf(v,0.125,0.75) in [0.625,0.875] -> one exponent for |v|<2
// -> uint-monotone mantissa; key = mant[22:3]<<12 | (4095-col).
// Partner merge snapshots before insert (round-7 lesson).
__global__ __launch_bounds__(256, 3) void k_simmfma(const char* __restrict__ xs2,
        unsigned int* __restrict__ topk) {
    __shared__ __align__(1024) char SMEM[24576];
    int bid = blockIdx.x;
    int img = bid & 15;
    int rest = bid >> 4;            // 0..174
    int rb = rest / NSEV;           // 0..24
    int sv = rest - rb * NSEV;      // 0..6
    int t = threadIdx.x;
    int w = t >> 6, lane = t & 63;
    int l31 = lane & 31, lh = lane >> 5;
    const char* xsi = xs2 + (size_t)img * 98 * TILEB;

    int r = rb * 128 + w * 32 + l31;
    bool valid = r < N_;
    int cbr = rb * 4 + w;           // wave's row tile (local cb)
    if (cbr > 97) cbr = 97;         // out-of-range waves (all-invalid): clamp
    bf16x8 bfrag[24];
    {
        const char* rp = xsi + (size_t)cbr * TILEB + lh * 512 + l31 * 16;
        #pragma unroll
        for (int kh = 0; kh < 2; ++kh)
            #pragma unroll
            for (int ks = 0; ks < 12; ++ks)
                bfrag[kh * 12 + ks] = *(const bf16x8*)(rp + kh * HALFB + ks * 1024);
    }
    unsigned int lk[12];
    #pragma unroll
    for (int k = 0; k < 12; ++k) lk[k] = 0u;

    int cbase = sv * SEVCOLS;
    int c_self = rb * 4 + w - sv * 14;   // wave-uniform diag chunk (may be out of [0,14))

    STAGETILE(SMEM, xsi, sv * 14, 0, 3)
    __syncthreads();

    for (int c = 0; c < 14; ++c) {
        STAGETILE(SMEM + HALFB, xsi, sv * 14 + c, 1, 3)
        f32x16 acc;
        #pragma unroll
        for (int i = 0; i < 16; ++i) acc[i] = 0.f;
        {
            const char* rp = SMEM + lh * 512 + l31 * 16;
            __builtin_amdgcn_s_setprio(1);
            #pragma unroll
            for (int ks = 0; ks < 12; ++ks) {
                bf16x8 af = *(const bf16x8*)(rp + ks * 1024);
                acc = __builtin_amdgcn_mfma_f32_32x32x16_bf16(af, bfrag[ks], acc, 0, 0, 0);
            }
            __builtin_amdgcn_s_setprio(0);
        }
        __syncthreads();
        if (c < 13) { STAGETILE(SMEM, xsi, sv * 14 + c + 1, 0, 3) }
        {
            const char* rp = SMEM + HALFB + lh * 512 + l31 * 16;
            __builtin_amdgcn_s_setprio(1);
            #pragma unroll
            for (int ks = 0; ks < 12; ++ks) {
                bf16x8 af = *(const bf16x8*)(rp + ks * 1024);
                acc = __builtin_amdgcn_mfma_f32_32x32x16_bf16(af, bfrag[12 + ks], acc, 0, 0, 0);
            }
            __builtin_amdgcn_s_setprio(0);
        }
        if (valid) {
            if (c == c_self) SCAN16D
            else             SCAN16
        }
        __syncthreads();
    }
    // merge partner lane: snapshot ALL partner keys first, then insert
    unsigned int pk[12];
    #pragma unroll
    for (int j = 0; j < 12; ++j)
        pk[j] = (unsigned int)__shfl_xor((int)lk[j], 32, 64);
    #pragma unroll
    for (int j = 0; j < 12; ++j) ins12m(lk, pk[j]);
    if (valid && lh == 0) {
        unsigned int* op = topk + ((size_t)sv * BN_ + (size_t)img * N_ + r) * 12;
        #pragma unroll
        for (int k = 0; k < 12; ++k) op[k] = lk[k];
    }
}

// ---------------- patch head via MFMA (K-split 24KB, occupancy 3) -------------
// Same bfrag[24] structure as simmfma: same spill cliff. Keep (256,3).
__global__ __launch_bounds__(256, 3) void k_patchmfma(const char* __restrict__ xs2,
        const unsigned short* __restrict__ wsc, const float* __restrict__ norms,
        const float* __restrict__ cb_, float* __restrict__ outp) {
    __shared__ __align__(1024) char SMEM[24576];
    int bid = blockIdx.x;
    int img = bid & 15;
    int n0 = (bid >> 4) * 64;
    int t = threadIdx.x;
    int w = t >> 6, lane = t & 63;
    int l31 = lane & 31, lh = lane >> 5;
    const char* xsi = xs2 + (size_t)img * 98 * TILEB;
    int ch = w * 32 + l31;
    bf16x8 bfrag[24];
    {
        const char* wp = (const char*)wsc + (size_t)ch * 768 + lh * 16;
        #pragma unroll
        for (int ks = 0; ks < 24; ++ks)
            bfrag[ks] = *(const bf16x8*)(wp + ks * 32);
    }
    float bias = (ch < NC_) ? cb_[ch] : 0.f;
    STAGETILE(SMEM, xsi, n0 >> 5, 0, 3)
    __syncthreads();
    for (int c = 0; c < 2; ++c) {
        STAGETILE(SMEM + HALFB, xsi, (n0 >> 5) + c, 1, 3)
        f32x16 acc;
        #pragma unroll
        for (int i = 0; i < 16; ++i) acc[i] = 0.f;
        {
            const char* rp = SMEM + lh * 512 + l31 * 16;
            #pragma unroll
            for (int ks = 0; ks < 12; ++ks) {
                bf16x8 af = *(const bf16x8*)(rp + ks * 1024);
                acc = __builtin_amdgcn_mfma_f32_32x32x16_bf16(af, bfrag[ks], acc, 0, 0, 0);
            }
        }
        __syncthreads();
        if (c == 0) { STAGETILE(SMEM, xsi, (n0 >> 5) + 1, 0, 3) }
        {
            const char* rp = SMEM + HALFB + lh * 512 + l31 * 16;
            #pragma unroll
            for (int ks = 0; ks < 12; ++ks) {
                bf16x8 af = *(const bf16x8*)(rp + ks * 1024);
                acc = __builtin_amdgcn_mfma_f32_32x32x16_bf16(af, bfrag[12 + ks], acc, 0, 0, 0);
            }
        }
        if (ch < NC_) {
            int nb = n0 + c * 32 + 4 * lh;
            float* op = outp + ((size_t)(img * NC_ + ch)) * N_ + nb;
            const float* npv = norms + (size_t)img * N_ + nb;
            #pragma unroll
            for (int g = 0; g < 4; ++g) {
                float4 nv = *(const float4*)(npv + 8 * g);
                float4 o;
                o.x = acc[4 * g + 0] * nv.x + bias;
                o.y = acc[4 * g + 1] * nv.y + bias;
                o.z = acc[4 * g + 2] * nv.z + bias;
                o.w = acc[4 * g + 3] * nv.w + bias;
                *(float4*)(op + 8 * g) = o;
            }
        }
        __syncthreads();
    }
}

// ---------------- GNN linear+relu via MFMA: h = relu(XS @ WSG^T + b) ---------
__global__ __launch_bounds__(384, 3) void k_gnnmfma(const char* __restrict__ xs2,
        const unsigned short* __restrict__ wsg, const float* __restrict__ gbias,
        float* __restrict__ h) {
    __shared__ __align__(1024) char SMEM[49152];
    int n0 = blockIdx.x * 128;
    int t = threadIdx.x;
    int w = t / 64, lane = t & 63;
    int l31 = lane & 31, lh = lane >> 5;
    int j = w * 32 + l31;
    bf16x8 bfrag[24];
    {
        const char* wp = (const char*)wsg + (size_t)j * 768 + lh * 16;
        #pragma unroll
        for (int ks = 0; ks < 24; ++ks)
            bfrag[ks] = *(const bf16x8*)(wp + ks * 32);
    }
    float bj = gbias[j];
    STAGEPAIR(SMEM, xs2, n0 >> 5, 4)
    __syncthreads();
    for (int c = 0; c < 4; ++c) {
        char* cur = SMEM + (c & 1) * 24576;
        if (c < 3) {
            char* dst = SMEM + ((c & 1) ^ 1) * 24576;
            STAGEPAIR(dst, xs2, (n0 >> 5) + c + 1, 4)
        }
        f32x16 acc;
        #pragma unroll
        for (int i = 0; i < 16; ++i) acc[i] = 0.f;
        const char* rp = cur + lh * 512 + l31 * 16;
        #pragma unroll
        for (int ks = 0; ks < 12; ++ks) {
            bf16x8 af = *(const bf16x8*)(rp + ks * 1024);
            acc = __builtin_amdgcn_mfma_f32_32x32x16_bf16(af, bfrag[ks], acc, 0, 0, 0);
        }
        #pragma unroll
        for (int ks = 0; ks < 12; ++ks) {
            bf16x8 af = *(const bf16x8*)(rp + HALFB + ks * 1024);
            acc = __builtin_amdgcn_mfma_f32_32x32x16_bf16(af, bfrag[12 + ks], acc, 0, 0, 0);
        }
        int nb = n0 + c * 32 + 4 * lh;
        #pragma unroll
        for (int g = 0; g < 4; ++g)
            #pragma unroll
            for (int q = 0; q < 4; ++q)
                h[(size_t)(nb + 8 * g + q) * C_ + j] = fmaxf(acc[4 * g + q] + bj, 0.f);
        __syncthreads();
    }
}

// ---------------- merge 7 per-seventh packed lists -> top-12 candidates -------
__global__ __launch_bounds__(256) void k_merge2(const unsigned int* __restrict__ topk,
        int* __restrict__ nbr12) {
    int row = blockIdx.x * 256 + threadIdx.x;      // 50176
    unsigned int lk[12];
    const unsigned int* p0 = topk + (size_t)row * 12;
    #pragma unroll
    for (int k = 0; k < 12; ++k) lk[k] = p0[k];
    #pragma unroll
    for (int h = 1; h < NSEV; ++h) {
        const unsigned int* p1 = topk + ((size_t)h * BN_ + row) * 12;
        #pragma unroll
        for (int j = 0; j < 12; ++j) ins12m(lk, p1[j]);
    }
    int gb = (row / N_) * N_;
    int* np = nbr12 + (size_t)row * 12;
    #pragma unroll
    for (int k = 0; k < 12; ++k) np[k] = gb + (4095 - (int)(lk[k] & 0xFFFu));
}

// -------- exact fp32 rescore, cooperative 16-lane (coalesced gathers) ---------
__global__ __launch_bounds__(256) void k_rescore(const float* __restrict__ xn,
        const int* __restrict__ nbr12, int* __restrict__ nbr9) {
    int img = blockIdx.x & 15;
    int sub = blockIdx.x >> 4;                     // 0..195
    int t = threadIdx.x;
    int nl = t >> 4, l16 = t & 15;
    int row = img * N_ + sub * 16 + nl;
    const float4* xa = (const float4*)(xn + (size_t)row * C_) + l16;
    float4 a0 = xa[0], a1 = xa[16], a2 = xa[32];
    const int* np12 = nbr12 + (size_t)row * 12;
    float d[12]; int ci[12];
    #pragma unroll
    for (int j = 0; j < 12; ++j) {
        int cand = np12[j];                        // wave-uniform per 16-group
        ci[j] = cand;
        const float4* xb = (const float4*)(xn + (size_t)cand * C_) + l16;
        float4 b0 = xb[0], b1 = xb[16], b2 = xb[32];
        float s = a0.x*b0.x + a0.y*b0.y + a0.z*b0.z + a0.w*b0.w
                + a1.x*b1.x + a1.y*b1.y + a1.z*b1.z + a1.w*b1.w
                + a2.x*b2.x + a2.y*b2.y + a2.z*b2.z + a2.w*b2.w;
        s += __shfl_xor(s, 1, 64);
        s += __shfl_xor(s, 2, 64);
        s += __shfl_xor(s, 4, 64);
        s += __shfl_xor(s, 8, 64);
        d[j] = (cand != row) ? s : -1e30f;
    }
    float lv[9]; int li[9];
    #pragma unroll
    for (int k = 0; k < 9; ++k) { lv[k] = -1e30f; li[k] = 0x7fffffff; }
    #pragma unroll
    for (int j = 0; j < 12; ++j) ins_lex<9>(lv, li, d[j], ci[j]);
    if (l16 == 0) {
        int* np = nbr9 + (size_t)row * 9;
        #pragma unroll
        for (int k = 0; k < 9; ++k) np[k] = li[k];
    }
}

// -------- edge attention + aggregation + pool partial (16 lanes/node) ---------
__global__ __launch_bounds__(256) void k_edge(const float* __restrict__ h,
        const int* __restrict__ nbr, float* __restrict__ eatt,
        float* __restrict__ gparte) {
    __shared__ float ps[4][C_];
    int img = blockIdx.x & 15;
    int sub = blockIdx.x >> 4;                     // 0..195
    int t = threadIdx.x;
    int wv = t >> 6;
    int nl = t >> 4;                               // node-local 0..15
    int l16 = t & 15;
    int node = img * N_ + sub * 16 + nl;
    const float4* hc = (const float4*)(h + (size_t)node * C_) + l16;
    float4 c0 = hc[0], c1 = hc[16], c2 = hc[32];
    float4 m0 = make_float4(0,0,0,0), m1 = make_float4(0,0,0,0), m2 = make_float4(0,0,0,0);
    const int* np_ = nbr + (size_t)node * K_;
    float* ep = eatt + (size_t)node * K_;
    #pragma unroll
    for (int k = 0; k < K_; ++k) {
        int src = np_[k];
        const float4* hs = (const float4*)(h + (size_t)src * C_) + l16;
        float4 s0 = hs[0], s1 = hs[16], s2 = hs[32];
        float d = s0.x*c0.x + s0.y*c0.y + s0.z*c0.z + s0.w*c0.w
                + s1.x*c1.x + s1.y*c1.y + s1.z*c1.z + s1.w*c1.w
                + s2.x*c2.x + s2.y*c2.y + s2.z*c2.z + s2.w*c2.w;
        d += __shfl_xor(d, 1, 64);
        d += __shfl_xor(d, 2, 64);
        d += __shfl_xor(d, 4, 64);
        d += __shfl_xor(d, 8, 64);
        if (l16 == 0) ep[k] = 1.0f / (1.0f + expf(-d));
        m0.x += s0.x; m0.y += s0.y; m0.z += s0.z; m0.w += s0.w;
        m1.x += s1.x; m1.y += s1.y; m1.z += s1.z; m1.w += s1.w;
        m2.x += s2.x; m2.y += s2.y; m2.z += s2.z; m2.w += s2.w;
    }
    const float r9 = 1.0f / 9.0f;
    float v[12];
    v[0] = c0.x + m0.x * r9; v[1]  = c0.y + m0.y * r9;
    v[2] = c0.z + m0.z * r9; v[3]  = c0.w + m0.w * r9;
    v[4] = c1.x + m1.x * r9; v[5]  = c1.y + m1.y * r9;
    v[6] = c1.z + m1.z * r9; v[7]  = c1.w + m1.w * r9;
    v[8] = c2.x + m2.x * r9; v[9]  = c2.y + m2.y * r9;
    v[10] = c2.z + m2.z * r9; v[11] = c2.w + m2.w * r9;
    #pragma unroll
    for (int e = 0; e < 12; ++e) {
        v[e] += __shfl_xor(v[e], 16, 64);
        v[e] += __shfl_xor(v[e], 32, 64);
    }
    if ((t & 63) < 16) {
        #pragma unroll
        for (int j = 0; j < 3; ++j)
            #pragma unroll
            for (int e = 0; e < 4; ++e)
                ps[wv][j * 64 + l16 * 4 + e] = v[j * 4 + e];
    }
    __syncthreads();
    if (t < C_)
        gparte[(size_t)blockIdx.x * C_ + t] =
            (ps[0][t] + ps[1][t]) + (ps[2][t] + ps[3][t]);
}

// ---------------- pool partials: 196 blocks/image -> 4 segments ---------------
__global__ __launch_bounds__(192) void k_gred(const float* __restrict__ gparte,
        float* __restrict__ gpart) {
    int b = blockIdx.x >> 2, s = blockIdx.x & 3;   // grid 64
    int oc = threadIdx.x;
    float acc = 0.f;
    for (int sub = s * 49; sub < (s + 1) * 49; ++sub)
        acc += gparte[((size_t)(sub * 16 + b)) * C_ + oc];
    gpart[(size_t)(b * 4 + s) * C_ + oc] = acc;
}

// ---------------- MLP stage 1: z = gs@w1+b1 -> BN -> GELU -> zs ---------------
__global__ __launch_bounds__(256) void k_mlp1(const float* __restrict__ gpart,
        const float* __restrict__ w1, const float* __restrict__ b1,
        const float* __restrict__ gam, const float* __restrict__ bet,
        float* __restrict__ zs) {
    __shared__ float gs[B_ * C_];
    int t = threadIdx.x;
    int j = blockIdx.x * 256 + t;                  // 0..1023
    for (int f = t; f < B_ * C_; f += 256) {
        int b = f / C_, oc = f - b * C_;
        float a = 0.f;
        #pragma unroll
        for (int s = 0; s < 4; ++s) a += gpart[((size_t)(b * 4 + s)) * C_ + oc];
        gs[f] = a;
    }
    __syncthreads();
    float z[16];
    #pragma unroll
    for (int i = 0; i < 16; ++i) z[i] = b1[j];
    for (int c = 0; c < C_; ++c) {
        float w = w1[(size_t)c * PD_ + j];
        #pragma unroll
        for (int i = 0; i < 16; ++i) z[i] += gs[i * C_ + c] * w;
    }
    float mu = 0.f;
    #pragma unroll
    for (int i = 0; i < 16; ++i) mu += z[i];
    mu *= (1.0f / 16.0f);
    float var = 0.f;
    #pragma unroll
    for (int i = 0; i < 16; ++i) { float d = z[i] - mu; var += d * d; }
    var *= (1.0f / 16.0f);
    float sc = (1.0f / sqrtf(var + 1e-5f)) * gam[j];
    float bt = bet[j];
    #pragma unroll
    for (int i = 0; i < 16; ++i) {
        float zh = (z[i] - mu) * sc + bt;
        zs[(size_t)i * PD_ + j] = 0.5f * zh * (1.0f + erff(zh * 0.70710678118654752f));
    }
}

// ---------------- MLP stage 2: pred = zs @ w2 + b2 (w2 pre-transposed) --------
__global__ __launch_bounds__(64) void k_mlp2(const float* __restrict__ zs,
        const float* __restrict__ w2t, const float* __restrict__ b2,
        float* __restrict__ pred) {
    int i = blockIdx.x / NC_, jj = blockIdx.x - i * NC_;
    int lane = threadIdx.x;
    const float* zr = zs + (size_t)i * PD_;
    const float* wr = w2t + (size_t)jj * PD_;
    float a = 0.f;
    #pragma unroll
    for (int k = 0; k < 16; ++k) a += zr[lane + 64 * k] * wr[lane + 64 * k];
    a += __shfl_xor(a, 1, 64);  a += __shfl_xor(a, 2, 64);
    a += __shfl_xor(a, 4, 64);  a += __shfl_xor(a, 8, 64);
    a += __shfl_xor(a, 16, 64); a += __shfl_xor(a, 32, 64);
    if (lane == 0) pred[i * NC_ + jj] = a + b2[jj];
}

extern "C" void kernel_launch(void* const* d_in, const int* in_sizes, int n_in,
                              void* d_out, int out_size, void* d_ws, size_t ws_size,
                              hipStream_t stream) {
    const float* img    = (const float*)d_in[0];
    const float* conv_w = (const float*)d_in[1];
    const float* conv_b = (const float*)d_in[2];
    const float* gnn_w  = (const float*)d_in[3];
    const float* gnn_b  = (const float*)d_in[4];
    const float* w1     = (const float*)d_in[5];
    const float* b1     = (const float*)d_in[6];
    const float* bng    = (const float*)d_in[7];
    const float* bnb    = (const float*)d_in[8];
    const float* w2     = (const float*)d_in[9];
    const float* b2     = (const float*)d_in[10];
    float* out = (float*)d_out;

    float* XN            = (float*)d_ws;                        // BN*192 f32
    char*  XS2           = (char*)(XN + (size_t)BN_ * C_);      // BN*768 bytes (tiled)
    unsigned int* TOPK   = (unsigned int*)(XS2 + (size_t)BN_ * 768);  // 7*BN*12
    int*   NBR12         = (int*)(TOPK + (size_t)NSEV * BN_ * 12);
    int*   NBR9          = NBR12 + (size_t)BN_ * 12;
    float* NORMS         = (float*)(NBR9 + (size_t)BN_ * K_);   // BN
    unsigned short* WSC  = (unsigned short*)(NORMS + BN_);      // 128*384
    unsigned short* WSG  = WSC + (size_t)128 * 384;             // 192*384
    float* GPART         = (float*)(WSG + (size_t)192 * 384);   // 64*C
    float* W2T           = GPART + (size_t)128 * C_;            // 100*1024
    float* Hh            = XN;            // reuse: XN dead after k_rescore
    float* GPARTE        = (float*)TOPK;  // reuse: TOPK dead after k_merge2
    float* ZS            = (float*)NBR12; // reuse: NBR12 dead after k_rescore

    k_normalize<<<784, 256, 0, stream>>>(img, XN, XS2, NORMS);
    k_wsplit   <<<640, 256, 0, stream>>>(conv_w, gnn_w, w2, WSC, WSG, W2T);
    k_patchmfma<<<784, 256, 0, stream>>>(XS2, WSC, NORMS, conv_b, out + OUT_PP);
    k_simmfma  <<<2800, 256, 0, stream>>>(XS2, TOPK);
    k_merge2   <<<196, 256, 0, stream>>>(TOPK, NBR12);
    k_rescore  <<<3136, 256, 0, stream>>>(XN, NBR12, NBR9);
    k_gnnmfma  <<<392, 384, 0, stream>>>(XS2, WSG, gnn_b, Hh);
    k_edge     <<<3136, 256, 0, stream>>>(Hh, NBR9, out + OUT_EATT, GPARTE);
    k_gred     <<<64, 192, 0, stream>>>(GPARTE, GPART);
    k_mlp1     <<<4, 256, 0, stream>>>(GPART, w1, b1, bng, bnb, ZS);
    k_mlp2     <<<1600, 64, 0, stream>>>(ZS, W2T, b2, out);
}

// Round 16
// 345.377 us; speedup vs baseline: 1.9041x; 1.0061x over previous
//
#include <hip/hip_runtime.h>
#include <math.h>

#define B_  16
#define C_  192
#define N_  3136
#define BN_ 50176
#define K_  9
#define NC_ 100
#define PD_ 1024
#define NSEV 7
#define SEVCOLS 448
#define TILEB 24576          // bytes per 32-col tile pair (hi+lo)
#define HALFB 12288

#define OUT_EATT 1600
#define OUT_PP   453184

typedef short bf16x8 __attribute__((ext_vector_type(8)));
typedef float f32x16 __attribute__((ext_vector_type(16)));

__device__ __forceinline__ unsigned int umaxu(unsigned int a, unsigned int b) { return a > b ? a : b; }
__device__ __forceinline__ unsigned int med3u(unsigned int a, unsigned int b, unsigned int c) {
    unsigned int d;
    asm("v_med3_u32 %0, %1, %2, %3" : "=v"(d) : "v"(a), "v"(b), "v"(c));
    return d;
}
// single insert step, ping-pong form (no array copy-back): dst = insert(src, key)
__device__ __forceinline__ void ins12p(const unsigned int (&s)[12], unsigned int (&d)[12],
                                       unsigned int key) {
    d[0] = umaxu(s[0], key);
    #pragma unroll
    for (int k = 1; k < 12; ++k) d[k] = med3u(s[k - 1], s[k], key);
}

// lexicographic (val desc, idx asc) insertion (rescore)
template<int NL>
__device__ inline void ins_lex(float (&lv)[NL], int (&li)[NL], float v, int vi) {
    if (v > lv[NL-1] || (v == lv[NL-1] && vi < li[NL-1])) {
        #pragma unroll
        for (int k = 0; k < NL; ++k) {
            bool p = (v > lv[k]) || (v == lv[k] && vi < li[k]);
            float fv = p ? lv[k] : v; int fi = p ? li[k] : vi;
            lv[k] = p ? v : lv[k];    li[k] = p ? vi : li[k];
            v = fv; vi = fi;
        }
    }
}

__device__ inline unsigned int bf16_rne(unsigned int u) {
    return (u + 0x7fffu + ((u >> 16) & 1u)) & 0xffff0000u;
}

// XS2 tiled layout: per 32-col block cb, per K-half kh: 12KB tile at
// cb*24576 + kh*12288; within: addr = ks*1024 + lh*512 + l31*16 + off.
// Exactly MFMA fragment consumption order -> all loads coalesced.

// ---------------- fused prep: normalize (blocks 0..783) + wsplit (784..1423) --
__global__ __launch_bounds__(256) void k_prep(const float* __restrict__ in,
        float* __restrict__ xn, char* __restrict__ xs2, float* __restrict__ norms,
        const float* __restrict__ cw, const float* __restrict__ gw,
        const float* __restrict__ w2, unsigned short* __restrict__ wsc,
        unsigned short* __restrict__ wsg, float* __restrict__ w2t) {
    __shared__ float tile[C_][65];
    __shared__ float part[4][64];
    __shared__ float rnorm_s[64];
    int t = threadIdx.x;
    if (blockIdx.x >= 784) {
        int id = (blockIdx.x - 784) * 256 + t;     // 640*256 = 163840
        if (id < 128 * 192) {
            int k = id / 192, c = id - k * 192;
            float v = (k < 100) ? cw[k * 192 + c] : 0.f;
            unsigned int h = bf16_rne(__float_as_uint(v));
            wsc[(size_t)k * 384 + c] = (unsigned short)(h >> 16);
            wsc[(size_t)k * 384 + 192 + c] =
                (unsigned short)(bf16_rne(__float_as_uint(v - __uint_as_float(h))) >> 16);
        } else if (id < 61440) {
            int e = id - 128 * 192;
            int cc = e / 192, j = e - cc * 192;
            float v = gw[cc * 192 + j];
            unsigned int h = bf16_rne(__float_as_uint(v));
            wsg[(size_t)j * 384 + cc] = (unsigned short)(h >> 16);
            wsg[(size_t)j * 384 + 192 + cc] =
                (unsigned short)(bf16_rne(__float_as_uint(v - __uint_as_float(h))) >> 16);
        } else {
            int e2 = id - 61440;                   // 0..102399
            int jj = e2 >> 10, k = e2 & 1023;
            w2t[(size_t)jj * PD_ + k] = w2[(size_t)k * NC_ + jj];
        }
        return;
    }
    int b = blockIdx.x & 15;
    int n0 = (blockIdx.x >> 4) * 64;
    for (int f = t; f < C_ * 64; f += 256) {
        int c = f >> 6, n = f & 63;
        tile[c][n] = in[((size_t)b * C_ + c) * N_ + n0 + n];
    }
    __syncthreads();
    {
        int n = t & 63, qq = t >> 6;
        float s = 0.f;
        #pragma unroll
        for (int i = 0; i < 48; ++i) { float v = tile[qq * 48 + i][n]; s += v * v; }
        part[qq][n] = s;
    }
    __syncthreads();
    if (t < 64) {
        float tot = part[0][t] + part[1][t] + part[2][t] + part[3][t];
        float nrm = fmaxf(sqrtf(tot), 1e-12f);
        norms[(size_t)b * N_ + n0 + t] = nrm;
        rnorm_s[t] = 1.0f / nrm;
    }
    __syncthreads();
    for (int f = t; f < 64 * 96; f += 256) {
        int n = f / 96, cp = f - n * 96;
        int c = cp * 2;
        float r = rnorm_s[n];
        float v0 = tile[c][n] * r;
        float v1 = tile[c + 1][n] * r;
        int row = b * N_ + n0 + n;
        *(float2*)(xn + (size_t)row * C_ + c) = make_float2(v0, v1);
        unsigned int h0 = bf16_rne(__float_as_uint(v0));
        unsigned int h1 = bf16_rne(__float_as_uint(v1));
        unsigned int l0 = bf16_rne(__float_as_uint(v0 - __uint_as_float(h0)));
        unsigned int l1 = bf16_rne(__float_as_uint(v1 - __uint_as_float(h1)));
        int cb = row >> 5, l31 = row & 31;
        int ks = cp >> 3, lh = (cp >> 2) & 1, off = 4 * (cp & 3);
        char* base = xs2 + (size_t)cb * TILEB + ks * 1024 + lh * 512 + l31 * 16 + off;
        *(unsigned int*)base           = (h0 >> 16) | (h1 & 0xffff0000u);
        *(unsigned int*)(base + HALFB) = (l0 >> 16) | (l1 & 0xffff0000u);
    }
}

// stage one 12KB tile-half (contiguous, coalesced); NLW glds/wave, NLW*waves=12
#define STAGETILE(DST, BASE, CB, KH, NLW) { \
    _Pragma("unroll") \
    for (int q_ = 0; q_ < NLW; ++q_) { \
        const char* s_ = (BASE) + (size_t)(CB) * TILEB + (KH) * HALFB + (w * (NLW) + q_) * 1024 + lane * 16; \
        __builtin_amdgcn_global_load_lds( \
            (const __attribute__((address_space(1))) unsigned int*)s_, \
            (__attribute__((address_space(3))) unsigned int*)((DST) + (w * (NLW) + q_) * 1024), 16, 0, 0); } }
// stage a full 24KB tile pair (gnn: 6 waves x 4 segs)
#define STAGEPAIR(DST, BASE, CB, NLW) { \
    _Pragma("unroll") \
    for (int q_ = 0; q_ < NLW; ++q_) { \
        const char* s_ = (BASE) + (size_t)(CB) * TILEB + (w * (NLW) + q_) * 1024 + lane * 16; \
        __builtin_amdgcn_global_load_lds( \
            (const __attribute__((address_space(1))) unsigned int*)s_, \
            (__attribute__((address_space(3))) unsigned int*)((DST) + (w * (NLW) + q_) * 1024), 16, 0, 0); } }

// 16-candidate packed-key scan (ping-pong inserts, even count -> ends in lk)
#define SCAN16 { \
    int c0 = cbase + c * 32 + 4 * lh; \
    int kc = 4095 - c0; \
    _Pragma("unroll") \
    for (int g = 0; g < 4; ++g) { \
        _Pragma("unroll") \
        for (int q = 0; q < 4; q += 2) { \
            unsigned int u0 = __float_as_uint(fmaf(acc[4 * g + q], 0.125f, 0.75f)); \
            unsigned int k0 = ((u0 >> 3) << 12) | (unsigned int)(kc - (8 * g + q)); \
            unsigned int u1 = __float_as_uint(fmaf(acc[4 * g + q + 1], 0.125f, 0.75f)); \
            unsigned int k1 = ((u1 >> 3) << 12) | (unsigned int)(kc - (8 * g + q + 1)); \
            ins12p(lk, nk, k0); \
            ins12p(nk, lk, k1); \
        } \
    } }
// diagonal-chunk variant: zero the self column
#define SCAN16D { \
    int c0 = cbase + c * 32 + 4 * lh; \
    int selfslot = r - c0; \
    int kc = 4095 - c0; \
    _Pragma("unroll") \
    for (int g = 0; g < 4; ++g) { \
        _Pragma("unroll") \
        for (int q = 0; q < 4; q += 2) { \
            unsigned int u0 = __float_as_uint(fmaf(acc[4 * g + q], 0.125f, 0.75f)); \
            unsigned int k0 = ((u0 >> 3) << 12) | (unsigned int)(kc - (8 * g + q)); \
            k0 = (8 * g + q == selfslot) ? 0u : k0; \
            unsigned int u1 = __float_as_uint(fmaf(acc[4 * g + q + 1], 0.125f, 0.75f)); \
            unsigned int k1 = ((u1 >> 3) << 12) | (unsigned int)(kc - (8 * g + q + 1)); \
            k1 = (8 * g + q + 1 == selfslot) ? 0u : k1; \
            ins12p(lk, nk, k0); \
            ins12p(nk, lk, k1); \
        } \
    } }

// ---------------- MFMA sim + branchless packed-u32 top-12 ----------
// grid 2800: img(16) x rowblk(25) x seventh(7). 4 waves x 32 rows = 128 rows.
// K-split double buffer (2x12KB), tiled XS2 (all loads coalesced).
// REGISTER GEOMETRY IS LOAD-BEARING: (256,3) -> no spill; (256,4)/(256,5)
// -> scratch spill (308/485us). DO NOT RAISE THE BOUND.
// Packed key: fmaf(v,0.125,0.75) in [0.625,0.875] -> one exponent for |v|<2
// -> uint-monotone mantissa; key = mant[22:3]<<12 | (4095-col).
// Partner merge snapshots before insert (round-7 lesson).
__global__ __launch_bounds__(256, 3) void k_simmfma(const char* __restrict__ xs2,
        unsigned int* __restrict__ topk) {
    __shared__ __align__(1024) char SMEM[24576];
    int bid = blockIdx.x;
    int img = bid & 15;
    int rest = bid >> 4;            // 0..174
    int rb = rest / NSEV;           // 0..24
    int sv = rest - rb * NSEV;      // 0..6
    int t = threadIdx.x;
    int w = t >> 6, lane = t & 63;
    int l31 = lane & 31, lh = lane >> 5;
    const char* xsi = xs2 + (size_t)img * 98 * TILEB;

    int r = rb * 128 + w * 32 + l31;
    bool valid = r < N_;
    int cbr = rb * 4 + w;           // wave's row tile (local cb)
    if (cbr > 97) cbr = 97;         // out-of-range waves (all-invalid): clamp
    bf16x8 bfrag[24];
    {
        const char* rp = xsi + (size_t)cbr * TILEB + lh * 512 + l31 * 16;
        #pragma unroll
        for (int kh = 0; kh < 2; ++kh)
            #pragma unroll
            for (int ks = 0; ks < 12; ++ks)
                bfrag[kh * 12 + ks] = *(const bf16x8*)(rp + kh * HALFB + ks * 1024);
    }
    unsigned int lk[12], nk[12];
    #pragma unroll
    for (int k = 0; k < 12; ++k) lk[k] = 0u;

    int cbase = sv * SEVCOLS;
    int c_self = rb * 4 + w - sv * 14;   // wave-uniform diag chunk (may be out of [0,14))

    STAGETILE(SMEM, xsi, sv * 14, 0, 3)
    __syncthreads();

    for (int c = 0; c < 14; ++c) {
        STAGETILE(SMEM + HALFB, xsi, sv * 14 + c, 1, 3)
        f32x16 acc;
        #pragma unroll
        for (int i = 0; i < 16; ++i) acc[i] = 0.f;
        {
            const char* rp = SMEM + lh * 512 + l31 * 16;
            __builtin_amdgcn_s_setprio(1);
            #pragma unroll
            for (int ks = 0; ks < 12; ++ks) {
                bf16x8 af = *(const bf16x8*)(rp + ks * 1024);
                acc = __builtin_amdgcn_mfma_f32_32x32x16_bf16(af, bfrag[ks], acc, 0, 0, 0);
            }
            __builtin_amdgcn_s_setprio(0);
        }
        __syncthreads();
        if (c < 13) { STAGETILE(SMEM, xsi, sv * 14 + c + 1, 0, 3) }
        {
            const char* rp = SMEM + HALFB + lh * 512 + l31 * 16;
            __builtin_amdgcn_s_setprio(1);
            #pragma unroll
            for (int ks = 0; ks < 12; ++ks) {
                bf16x8 af = *(const bf16x8*)(rp + ks * 1024);
                acc = __builtin_amdgcn_mfma_f32_32x32x16_bf16(af, bfrag[12 + ks], acc, 0, 0, 0);
            }
            __builtin_amdgcn_s_setprio(0);
        }
        if (valid) {
            if (c == c_self) SCAN16D
            else             SCAN16
        }
        __syncthreads();
    }
    // merge partner lane: snapshot ALL partner keys first, then insert (12 = even)
    unsigned int pk[12];
    #pragma unroll
    for (int j = 0; j < 12; ++j)
        pk[j] = (unsigned int)__shfl_xor((int)lk[j], 32, 64);
    #pragma unroll
    for (int j = 0; j < 12; j += 2) {
        ins12p(lk, nk, pk[j]);
        ins12p(nk, lk, pk[j + 1]);
    }
    if (valid && lh == 0) {
        unsigned int* op = topk + ((size_t)sv * BN_ + (size_t)img * N_ + r) * 12;
        #pragma unroll
        for (int k = 0; k < 12; ++k) op[k] = lk[k];
    }
}

// ---------------- patch head via MFMA (K-split 24KB, occupancy 3) -------------
// Same bfrag[24] structure as simmfma: same spill cliff. Keep (256,3).
__global__ __launch_bounds__(256, 3) void k_patchmfma(const char* __restrict__ xs2,
        const unsigned short* __restrict__ wsc, const float* __restrict__ norms,
        const float* __restrict__ cb_, float* __restrict__ outp) {
    __shared__ __align__(1024) char SMEM[24576];
    int bid = blockIdx.x;
    int img = bid & 15;
    int n0 = (bid >> 4) * 64;
    int t = threadIdx.x;
    int w = t >> 6, lane = t & 63;
    int l31 = lane & 31, lh = lane >> 5;
    const char* xsi = xs2 + (size_t)img * 98 * TILEB;
    int ch = w * 32 + l31;
    bf16x8 bfrag[24];
    {
        const char* wp = (const char*)wsc + (size_t)ch * 768 + lh * 16;
        #pragma unroll
        for (int ks = 0; ks < 24; ++ks)
            bfrag[ks] = *(const bf16x8*)(wp + ks * 32);
    }
    float bias = (ch < NC_) ? cb_[ch] : 0.f;
    STAGETILE(SMEM, xsi, n0 >> 5, 0, 3)
    __syncthreads();
    for (int c = 0; c < 2; ++c) {
        STAGETILE(SMEM + HALFB, xsi, (n0 >> 5) + c, 1, 3)
        f32x16 acc;
        #pragma unroll
        for (int i = 0; i < 16; ++i) acc[i] = 0.f;
        {
            const char* rp = SMEM + lh * 512 + l31 * 16;
            #pragma unroll
            for (int ks = 0; ks < 12; ++ks) {
                bf16x8 af = *(const bf16x8*)(rp + ks * 1024);
                acc = __builtin_amdgcn_mfma_f32_32x32x16_bf16(af, bfrag[ks], acc, 0, 0, 0);
            }
        }
        __syncthreads();
        if (c == 0) { STAGETILE(SMEM, xsi, (n0 >> 5) + 1, 0, 3) }
        {
            const char* rp = SMEM + HALFB + lh * 512 + l31 * 16;
            #pragma unroll
            for (int ks = 0; ks < 12; ++ks) {
                bf16x8 af = *(const bf16x8*)(rp + ks * 1024);
                acc = __builtin_amdgcn_mfma_f32_32x32x16_bf16(af, bfrag[12 + ks], acc, 0, 0, 0);
            }
        }
        if (ch < NC_) {
            int nb = n0 + c * 32 + 4 * lh;
            float* op = outp + ((size_t)(img * NC_ + ch)) * N_ + nb;
            const float* npv = norms + (size_t)img * N_ + nb;
            #pragma unroll
            for (int g = 0; g < 4; ++g) {
                float4 nv = *(const float4*)(npv + 8 * g);
                float4 o;
                o.x = acc[4 * g + 0] * nv.x + bias;
                o.y = acc[4 * g + 1] * nv.y + bias;
                o.z = acc[4 * g + 2] * nv.z + bias;
                o.w = acc[4 * g + 3] * nv.w + bias;
                *(float4*)(op + 8 * g) = o;
            }
        }
        __syncthreads();
    }
}

// ---------------- GNN linear+relu via MFMA: h = relu(XS @ WSG^T + b) ---------
__global__ __launch_bounds__(384, 3) void k_gnnmfma(const char* __restrict__ xs2,
        const unsigned short* __restrict__ wsg, const float* __restrict__ gbias,
        float* __restrict__ h) {
    __shared__ __align__(1024) char SMEM[49152];
    int n0 = blockIdx.x * 128;
    int t = threadIdx.x;
    int w = t / 64, lane = t & 63;
    int l31 = lane & 31, lh = lane >> 5;
    int j = w * 32 + l31;
    bf16x8 bfrag[24];
    {
        const char* wp = (const char*)wsg + (size_t)j * 768 + lh * 16;
        #pragma unroll
        for (int ks = 0; ks < 24; ++ks)
            bfrag[ks] = *(const bf16x8*)(wp + ks * 32);
    }
    float bj = gbias[j];
    STAGEPAIR(SMEM, xs2, n0 >> 5, 4)
    __syncthreads();
    for (int c = 0; c < 4; ++c) {
        char* cur = SMEM + (c & 1) * 24576;
        if (c < 3) {
            char* dst = SMEM + ((c & 1) ^ 1) * 24576;
            STAGEPAIR(dst, xs2, (n0 >> 5) + c + 1, 4)
        }
        f32x16 acc;
        #pragma unroll
        for (int i = 0; i < 16; ++i) acc[i] = 0.f;
        const char* rp = cur + lh * 512 + l31 * 16;
        #pragma unroll
        for (int ks = 0; ks < 12; ++ks) {
            bf16x8 af = *(const bf16x8*)(rp + ks * 1024);
            acc = __builtin_amdgcn_mfma_f32_32x32x16_bf16(af, bfrag[ks], acc, 0, 0, 0);
        }
        #pragma unroll
        for (int ks = 0; ks < 12; ++ks) {
            bf16x8 af = *(const bf16x8*)(rp + HALFB + ks * 1024);
            acc = __builtin_amdgcn_mfma_f32_32x32x16_bf16(af, bfrag[12 + ks], acc, 0, 0, 0);
        }
        int nb = n0 + c * 32 + 4 * lh;
        #pragma unroll
        for (int g = 0; g < 4; ++g)
            #pragma unroll
            for (int q = 0; q < 4; ++q)
                h[(size_t)(nb + 8 * g + q) * C_ + j] = fmaxf(acc[4 * g + q] + bj, 0.f);
        __syncthreads();
    }
}

// ---------------- merge 7 per-seventh packed lists -> top-12 candidates -------
__global__ __launch_bounds__(256) void k_merge2(const unsigned int* __restrict__ topk,
        int* __restrict__ nbr12) {
    int row = blockIdx.x * 256 + threadIdx.x;      // 50176
    unsigned int lk[12], nk[12];
    const unsigned int* p0 = topk + (size_t)row * 12;
    #pragma unroll
    for (int k = 0; k < 12; ++k) lk[k] = p0[k];
    #pragma unroll
    for (int h = 1; h < NSEV; ++h) {
        const unsigned int* p1 = topk + ((size_t)h * BN_ + row) * 12;
        #pragma unroll
        for (int j = 0; j < 12; j += 2) {
            ins12p(lk, nk, p1[j]);
            ins12p(nk, lk, p1[j + 1]);
        }
    }
    int gb = (row / N_) * N_;
    int* np = nbr12 + (size_t)row * 12;
    #pragma unroll
    for (int k = 0; k < 12; ++k) np[k] = gb + (4095 - (int)(lk[k] & 0xFFFu));
}

// -------- exact fp32 rescore, cooperative 16-lane (coalesced gathers) ---------
__global__ __launch_bounds__(256) void k_rescore(const float* __restrict__ xn,
        const int* __restrict__ nbr12, int* __restrict__ nbr9) {
    int img = blockIdx.x & 15;
    int sub = blockIdx.x >> 4;                     // 0..195
    int t = threadIdx.x;
    int nl = t >> 4, l16 = t & 15;
    int row = img * N_ + sub * 16 + nl;
    const float4* xa = (const float4*)(xn + (size_t)row * C_) + l16;
    float4 a0 = xa[0], a1 = xa[16], a2 = xa[32];
    const int* np12 = nbr12 + (size_t)row * 12;
    float d[12]; int ci[12];
    #pragma unroll
    for (int j = 0; j < 12; ++j) {
        int cand = np12[j];                        // wave-uniform per 16-group
        ci[j] = cand;
        const float4* xb = (const float4*)(xn + (size_t)cand * C_) + l16;
        float4 b0 = xb[0], b1 = xb[16], b2 = xb[32];
        float s = a0.x*b0.x + a0.y*b0.y + a0.z*b0.z + a0.w*b0.w
                + a1.x*b1.x + a1.y*b1.y + a1.z*b1.z + a1.w*b1.w
                + a2.x*b2.x + a2.y*b2.y + a2.z*b2.z + a2.w*b2.w;
        s += __shfl_xor(s, 1, 64);
        s += __shfl_xor(s, 2, 64);
        s += __shfl_xor(s, 4, 64);
        s += __shfl_xor(s, 8, 64);
        d[j] = (cand != row) ? s : -1e30f;
    }
    float lv[9]; int li[9];
    #pragma unroll
    for (int k = 0; k < 9; ++k) { lv[k] = -1e30f; li[k] = 0x7fffffff; }
    #pragma unroll
    for (int j = 0; j < 12; ++j) ins_lex<9>(lv, li, d[j], ci[j]);
    if (l16 == 0) {
        int* np = nbr9 + (size_t)row * 9;
        #pragma unroll
        for (int k = 0; k < 9; ++k) np[k] = li[k];
    }
}

// -------- edge attention + aggregation + pool partial (16 lanes/node) ---------
__global__ __launch_bounds__(256) void k_edge(const float* __restrict__ h,
        const int* __restrict__ nbr, float* __restrict__ eatt,
        float* __restrict__ gparte) {
    __shared__ float ps[4][C_];
    int img = blockIdx.x & 15;
    int sub = blockIdx.x >> 4;                     // 0..195
    int t = threadIdx.x;
    int wv = t >> 6;
    int nl = t >> 4;                               // node-local 0..15
    int l16 = t & 15;
    int node = img * N_ + sub * 16 + nl;
    const float4* hc = (const float4*)(h + (size_t)node * C_) + l16;
    float4 c0 = hc[0], c1 = hc[16], c2 = hc[32];
    float4 m0 = make_float4(0,0,0,0), m1 = make_float4(0,0,0,0), m2 = make_float4(0,0,0,0);
    const int* np_ = nbr + (size_t)node * K_;
    float* ep = eatt + (size_t)node * K_;
    #pragma unroll
    for (int k = 0; k < K_; ++k) {
        int src = np_[k];
        const float4* hs = (const float4*)(h + (size_t)src * C_) + l16;
        float4 s0 = hs[0], s1 = hs[16], s2 = hs[32];
        float d = s0.x*c0.x + s0.y*c0.y + s0.z*c0.z + s0.w*c0.w
                + s1.x*c1.x + s1.y*c1.y + s1.z*c1.z + s1.w*c1.w
                + s2.x*c2.x + s2.y*c2.y + s2.z*c2.z + s2.w*c2.w;
        d += __shfl_xor(d, 1, 64);
        d += __shfl_xor(d, 2, 64);
        d += __shfl_xor(d, 4, 64);
        d += __shfl_xor(d, 8, 64);
        if (l16 == 0) ep[k] = 1.0f / (1.0f + expf(-d));
        m0.x += s0.x; m0.y += s0.y; m0.z += s0.z; m0.w += s0.w;
        m1.x += s1.x; m1.y += s1.y; m1.z += s1.z; m1.w += s1.w;
        m2.x += s2.x; m2.y += s2.y; m2.z += s2.z; m2.w += s2.w;
    }
    const float r9 = 1.0f / 9.0f;
    float v[12];
    v[0] = c0.x + m0.x * r9; v[1]  = c0.y + m0.y * r9;
    v[2] = c0.z + m0.z * r9; v[3]  = c0.w + m0.w * r9;
    v[4] = c1.x + m1.x * r9; v[5]  = c1.y + m1.y * r9;
    v[6] = c1.z + m1.z * r9; v[7]  = c1.w + m1.w * r9;
    v[8] = c2.x + m2.x * r9; v[9]  = c2.y + m2.y * r9;
    v[10] = c2.z + m2.z * r9; v[11] = c2.w + m2.w * r9;
    #pragma unroll
    for (int e = 0; e < 12; ++e) {
        v[e] += __shfl_xor(v[e], 16, 64);
        v[e] += __shfl_xor(v[e], 32, 64);
    }
    if ((t & 63) < 16) {
        #pragma unroll
        for (int j = 0; j < 3; ++j)
            #pragma unroll
            for (int e = 0; e < 4; ++e)
                ps[wv][j * 64 + l16 * 4 + e] = v[j * 4 + e];
    }
    __syncthreads();
    if (t < C_)
        gparte[(size_t)blockIdx.x * C_ + t] =
            (ps[0][t] + ps[1][t]) + (ps[2][t] + ps[3][t]);
}

// ---------------- pool partials: 196 blocks/image -> 4 segments ---------------
__global__ __launch_bounds__(192) void k_gred(const float* __restrict__ gparte,
        float* __restrict__ gpart) {
    int b = blockIdx.x >> 2, s = blockIdx.x & 3;   // grid 64
    int oc = threadIdx.x;
    float acc = 0.f;
    for (int sub = s * 49; sub < (s + 1) * 49; ++sub)
        acc += gparte[((size_t)(sub * 16 + b)) * C_ + oc];
    gpart[(size_t)(b * 4 + s) * C_ + oc] = acc;
}

// ---------------- MLP stage 1: z = gs@w1+b1 -> BN -> GELU -> zs ---------------
__global__ __launch_bounds__(256) void k_mlp1(const float* __restrict__ gpart,
        const float* __restrict__ w1, const float* __restrict__ b1,
        const float* __restrict__ gam, const float* __restrict__ bet,
        float* __restrict__ zs) {
    __shared__ float gs[B_ * C_];
    int t = threadIdx.x;
    int j = blockIdx.x * 256 + t;                  // 0..1023
    for (int f = t; f < B_ * C_; f += 256) {
        int b = f / C_, oc = f - b * C_;
        float a = 0.f;
        #pragma unroll
        for (int s = 0; s < 4; ++s) a += gpart[((size_t)(b * 4 + s)) * C_ + oc];
        gs[f] = a;
    }
    __syncthreads();
    float z[16];
    #pragma unroll
    for (int i = 0; i < 16; ++i) z[i] = b1[j];
    for (int c = 0; c < C_; ++c) {
        float w = w1[(size_t)c * PD_ + j];
        #pragma unroll
        for (int i = 0; i < 16; ++i) z[i] += gs[i * C_ + c] * w;
    }
    float mu = 0.f;
    #pragma unroll
    for (int i = 0; i < 16; ++i) mu += z[i];
    mu *= (1.0f / 16.0f);
    float var = 0.f;
    #pragma unroll
    for (int i = 0; i < 16; ++i) { float d = z[i] - mu; var += d * d; }
    var *= (1.0f / 16.0f);
    float sc = (1.0f / sqrtf(var + 1e-5f)) * gam[j];
    float bt = bet[j];
    #pragma unroll
    for (int i = 0; i < 16; ++i) {
        float zh = (z[i] - mu) * sc + bt;
        zs[(size_t)i * PD_ + j] = 0.5f * zh * (1.0f + erff(zh * 0.70710678118654752f));
    }
}

// ---------------- MLP stage 2: pred = zs @ w2 + b2 (w2 pre-transposed) --------
__global__ __launch_bounds__(64) void k_mlp2(const float* __restrict__ zs,
        const float* __restrict__ w2t, const float* __restrict__ b2,
        float* __restrict__ pred) {
    int i = blockIdx.x / NC_, jj = blockIdx.x - i * NC_;
    int lane = threadIdx.x;
    const float* zr = zs + (size_t)i * PD_;
    const float* wr = w2t + (size_t)jj * PD_;
    float a = 0.f;
    #pragma unroll
    for (int k = 0; k < 16; ++k) a += zr[lane + 64 * k] * wr[lane + 64 * k];
    a += __shfl_xor(a, 1, 64);  a += __shfl_xor(a, 2, 64);
    a += __shfl_xor(a, 4, 64);  a += __shfl_xor(a, 8, 64);
    a += __shfl_xor(a, 16, 64); a += __shfl_xor(a, 32, 64);
    if (lane == 0) pred[i * NC_ + jj] = a + b2[jj];
}

extern "C" void kernel_launch(void* const* d_in, const int* in_sizes, int n_in,
                              void* d_out, int out_size, void* d_ws, size_t ws_size,
                              hipStream_t stream) {
    const float* img    = (const float*)d_in[0];
    const float* conv_w = (const float*)d_in[1];
    const float* conv_b = (const float*)d_in[2];
    const float* gnn_w  = (const float*)d_in[3];
    const float* gnn_b  = (const float*)d_in[4];
    const float* w1     = (const float*)d_in[5];
    const float* b1     = (const float*)d_in[6];
    const float* bng    = (const float*)d_in[7];
    const float* bnb    = (const float*)d_in[8];
    const float* w2     = (const float*)d_in[9];
    const float* b2     = (const float*)d_in[10];
    float* out = (float*)d_out;

    float* XN            = (float*)d_ws;                        // BN*192 f32
    char*  XS2           = (char*)(XN + (size_t)BN_ * C_);      // BN*768 bytes (tiled)
    unsigned int* TOPK   = (unsigned int*)(XS2 + (size_t)BN_ * 768);  // 7*BN*12
    int*   NBR12         = (int*)(TOPK + (size_t)NSEV * BN_ * 12);
    int*   NBR9          = NBR12 + (size_t)BN_ * 12;
    float* NORMS         = (float*)(NBR9 + (size_t)BN_ * K_);   // BN
    unsigned short* WSC  = (unsigned short*)(NORMS + BN_);      // 128*384
    unsigned short* WSG  = WSC + (size_t)128 * 384;             // 192*384
    float* GPART         = (float*)(WSG + (size_t)192 * 384);   // 64*C
    float* W2T           = GPART + (size_t)128 * C_;            // 100*1024
    float* Hh            = XN;            // reuse: XN dead after k_rescore
    float* GPARTE        = (float*)TOPK;  // reuse: TOPK dead after k_merge2
    float* ZS            = (float*)NBR12; // reuse: NBR12 dead after k_rescore

    k_prep     <<<1424, 256, 0, stream>>>(img, XN, XS2, NORMS,
                                          conv_w, gnn_w, w2, WSC, WSG, W2T);
    k_patchmfma<<<784, 256, 0, stream>>>(XS2, WSC, NORMS, conv_b, out + OUT_PP);
    k_simmfma  <<<2800, 256, 0, stream>>>(XS2, TOPK);
    k_merge2   <<<196, 256, 0, stream>>>(TOPK, NBR12);
    k_rescore  <<<3136, 256, 0, stream>>>(XN, NBR12, NBR9);
    k_gnnmfma  <<<392, 384, 0, stream>>>(XS2, WSG, gnn_b, Hh);
    k_edge     <<<3136, 256, 0, stream>>>(Hh, NBR9, out + OUT_EATT, GPARTE);
    k_gred     <<<64, 192, 0, stream>>>(GPARTE, GPART);
    k_mlp1     <<<4, 256, 0, stream>>>(GPART, w1, b1, bng, bnb, ZS);
    k_mlp2     <<<1600, 64, 0, stream>>>(ZS, W2T, b2, out);
}